// Round 4
// baseline (787.008 us; speedup 1.0000x reference)
//
#include <hip/hip_runtime.h>
#include <stdint.h>

// ---------------------------------------------------------------- CSR build
// NOTE: harness passes integer inputs as int32 (edge_index is const int*),
// regardless of the reference's declared int64. Reading as long long was the
// Round-2/3 crash (OOB reads + wild atomic addresses).

__global__ void hist_k(const int* __restrict__ ei, int* __restrict__ deg, int E) {
    int e = blockIdx.x * blockDim.x + threadIdx.x;
    if (e >= E) return;
    int t = ei[(size_t)E + e];                // tgt row of edge_index
    atomicAdd(&deg[t], 1);
}

__global__ void scan_block_k(const int* __restrict__ deg, int* __restrict__ excl,
                             int* __restrict__ bsum, int N) {
    __shared__ int sd[256];
    int t = threadIdx.x;
    int base = blockIdx.x * 1024 + t * 4;
    int v0 = (base + 0 < N) ? deg[base + 0] : 0;
    int v1 = (base + 1 < N) ? deg[base + 1] : 0;
    int v2 = (base + 2 < N) ? deg[base + 2] : 0;
    int v3 = (base + 3 < N) ? deg[base + 3] : 0;
    int s = v0 + v1 + v2 + v3;
    sd[t] = s;
    __syncthreads();
    for (int off = 1; off < 256; off <<= 1) {
        int x = (t >= off) ? sd[t - off] : 0;
        __syncthreads();
        sd[t] += x;
        __syncthreads();
    }
    int incl = sd[t];
    int ex = incl - s;
    if (base + 0 < N) excl[base + 0] = ex;
    if (base + 1 < N) excl[base + 1] = ex + v0;
    if (base + 2 < N) excl[base + 2] = ex + v0 + v1;
    if (base + 3 < N) excl[base + 3] = ex + v0 + v1 + v2;
    if (t == 255) bsum[blockIdx.x] = incl;
}

__global__ void scan_sums_k(const int* __restrict__ bsum, int* __restrict__ boff, int nb) {
    if (threadIdx.x == 0) {
        int acc = 0;
        for (int i = 0; i < nb; ++i) { boff[i] = acc; acc += bsum[i]; }
    }
}

__global__ void add_off_k(int* rs, int* cursor, const int* __restrict__ boff, int N, int E) {
    int i = blockIdx.x * blockDim.x + threadIdx.x;
    if (i < N) {
        int v = rs[i] + boff[i >> 10];
        rs[i] = v;
        cursor[i] = v;
    }
    if (i == 0) rs[N] = E;
}

__global__ void fill_k(const int* __restrict__ ei, int* cursor,
                       int* __restrict__ csr, int E) {
    int e = blockIdx.x * blockDim.x + threadIdx.x;
    if (e >= E) return;
    int s = ei[e];                            // src
    int t = ei[(size_t)E + e];                // tgt
    int p = atomicAdd(&cursor[t], 1);
    csr[p] = s;
}

// ------------------------------------------------------------- aggregation

// Layer-1 aggregation, F=9: one thread per node.
__global__ void agg9_k(const float* __restrict__ x, const int* __restrict__ rs,
                       const int* __restrict__ csr, float* __restrict__ agg, int N) {
    int i = blockIdx.x * blockDim.x + threadIdx.x;
    if (i >= N) return;
    int s0 = rs[i], s1 = rs[i + 1];
    float a[9];
    #pragma unroll
    for (int f = 0; f < 9; ++f) a[f] = 0.f;
    for (int j = s0; j < s1; ++j) {
        const float* p = x + (size_t)csr[j] * 9;
        #pragma unroll
        for (int f = 0; f < 9; ++f) a[f] += p[f];
    }
    float inv = (s1 > s0) ? 1.f / (float)(s1 - s0) : 0.f;
    float* o = agg + (size_t)i * 9;
    #pragma unroll
    for (int f = 0; f < 9; ++f) o[f] = a[f] * inv;
}

// F=128 aggregation: one wave per node, float2 per lane (512B/row in 1 instr).
__global__ __launch_bounds__(256) void agg128_k(const float* __restrict__ h,
        const int* __restrict__ rs, const int* __restrict__ csr,
        float* __restrict__ out, int N) {
    int lane = threadIdx.x & 63;
    int node = blockIdx.x * 4 + (threadIdx.x >> 6);
    if (node >= N) return;
    int s0 = rs[node], s1 = rs[node + 1];
    const float2* h2 = reinterpret_cast<const float2*>(h);
    float ax = 0.f, ay = 0.f;
    int j = s0;
    for (; j + 4 <= s1; j += 4) {
        int n0 = csr[j], n1 = csr[j + 1], n2 = csr[j + 2], n3 = csr[j + 3];
        float2 v0 = h2[(size_t)n0 * 64 + lane];
        float2 v1 = h2[(size_t)n1 * 64 + lane];
        float2 v2 = h2[(size_t)n2 * 64 + lane];
        float2 v3 = h2[(size_t)n3 * 64 + lane];
        ax += (v0.x + v1.x) + (v2.x + v3.x);
        ay += (v0.y + v1.y) + (v2.y + v3.y);
    }
    for (; j < s1; ++j) {
        float2 v = h2[(size_t)csr[j] * 64 + lane];
        ax += v.x;
        ay += v.y;
    }
    float inv = (s1 > s0) ? 1.f / (float)(s1 - s0) : 0.f;
    float2 r;
    r.x = ax * inv;
    r.y = ay * inv;
    reinterpret_cast<float2*>(out)[(size_t)node * 64 + lane] = r;
}

// ------------------------------------------------------------------- GEMMs

// Layer-1 linear: K=9, out = relu(agg@Wl + x@Wr + b). One thread per (node,col).
__global__ void lin1_k(const float* __restrict__ agg, const float* __restrict__ x,
                       const float* __restrict__ Wl, const float* __restrict__ Wr,
                       const float* __restrict__ b, float* __restrict__ out, int N) {
    int idx = blockIdx.x * blockDim.x + threadIdx.x;
    if (idx >= N * 128) return;
    int i = idx >> 7, c = idx & 127;
    float acc = b[c];
    const float* ar = agg + (size_t)i * 9;
    const float* xr = x + (size_t)i * 9;
    #pragma unroll
    for (int k = 0; k < 9; ++k)
        acc += ar[k] * Wl[k * 128 + c] + xr[k] * Wr[k * 128 + c];
    out[idx] = fmaxf(acc, 0.f);
}

// Tiled fp32 GEMM: C[M,TN] = act(A1@W1 (+ A2@W2) + bias).
// TM=64 rows/block, full output width per block (TN=128 or 64), K multiple of 32.
// NOTE: A/C intentionally NOT __restrict__ — several calls are row-wise in-place.
template<int TN, bool DUAL, bool RELU>
__global__ __launch_bounds__(256) void lin_k(
        const float* A1, const float* __restrict__ W1, int K1,
        const float* A2, const float* __restrict__ W2, int K2,
        const float* __restrict__ bias, float* C, int M) {
    constexpr int TM = 64;
    constexpr int TCOLS = TN / 4;        // 32 or 16
    constexpr int TROWS = 256 / TCOLS;   // 8 or 16
    constexpr int RPT = TM / TROWS;      // 8 or 4 rows per thread
    constexpr int NS = DUAL ? 2 : 1;

    __shared__ float a_lds[TM][36];      // stride 36 floats = 144B (16B multiple)
    __shared__ float w_lds[32][TN];

    int tid = threadIdx.x;
    int tc = tid % TCOLS;
    int tr = tid / TCOLS;
    int rb = blockIdx.x * TM;

    float4 bv = *reinterpret_cast<const float4*>(bias + tc * 4);
    float acc[RPT][4];
    #pragma unroll
    for (int m = 0; m < RPT; ++m) {
        acc[m][0] = bv.x; acc[m][1] = bv.y; acc[m][2] = bv.z; acc[m][3] = bv.w;
    }

    const float* As[2] = {A1, A2};
    const float* Ws[2] = {W1, W2};
    int Ks[2] = {K1, K2};

    for (int s = 0; s < NS; ++s) {
        const float* A = As[s];
        const float* W = Ws[s];
        const int K = Ks[s];
        for (int kt = 0; kt < K; kt += 32) {
            __syncthreads();
            {   // stage A tile: 64 rows x 32 cols, float4 coalesced
                int c4 = (tid & 7) * 4;
                int r = tid >> 3;
                #pragma unroll
                for (int i = 0; i < 2; ++i) {
                    int rr = r + i * 32;
                    int grow = rb + rr;
                    float4 v = make_float4(0.f, 0.f, 0.f, 0.f);
                    if (grow < M)
                        v = *reinterpret_cast<const float4*>(A + (size_t)grow * K + kt + c4);
                    *reinterpret_cast<float4*>(&a_lds[rr][c4]) = v;
                }
            }
            {   // stage W tile: 32 rows x TN cols, float4 coalesced
                constexpr int ITER = (32 * TN) / 1024;
                #pragma unroll
                for (int i = 0; i < ITER; ++i) {
                    int lin4 = (tid + i * 256) * 4;
                    int r = lin4 / TN;
                    int c = lin4 % TN;
                    *reinterpret_cast<float4*>(&w_lds[r][c]) =
                        *reinterpret_cast<const float4*>(W + (size_t)(kt + r) * TN + c);
                }
            }
            __syncthreads();
            #pragma unroll
            for (int k = 0; k < 32; ++k) {
                float4 wv = *reinterpret_cast<const float4*>(&w_lds[k][tc * 4]);
                #pragma unroll
                for (int m = 0; m < RPT; ++m) {
                    float a = a_lds[tr * RPT + m][k];
                    acc[m][0] = fmaf(a, wv.x, acc[m][0]);
                    acc[m][1] = fmaf(a, wv.y, acc[m][1]);
                    acc[m][2] = fmaf(a, wv.z, acc[m][2]);
                    acc[m][3] = fmaf(a, wv.w, acc[m][3]);
                }
            }
        }
    }
    #pragma unroll
    for (int m = 0; m < RPT; ++m) {
        int grow = rb + tr * RPT + m;
        if (grow < M) {
            float4 v;
            v.x = acc[m][0]; v.y = acc[m][1]; v.z = acc[m][2]; v.w = acc[m][3];
            if (RELU) {
                v.x = fmaxf(v.x, 0.f); v.y = fmaxf(v.y, 0.f);
                v.z = fmaxf(v.z, 0.f); v.w = fmaxf(v.w, 0.f);
            }
            *reinterpret_cast<float4*>(C + (size_t)grow * TN + tc * 4) = v;
        }
    }
}

// Final: [N,64] @ [64,3] + b, then log_softmax. One thread per node.
__global__ void final_k(const float* __restrict__ m2, const float* __restrict__ W,
                        const float* __restrict__ b, float* __restrict__ out, int N) {
    int i = blockIdx.x * blockDim.x + threadIdx.x;
    if (i >= N) return;
    const float* r = m2 + (size_t)i * 64;
    float l0 = b[0], l1 = b[1], l2 = b[2];
    #pragma unroll 8
    for (int k = 0; k < 64; ++k) {
        float v = r[k];
        l0 = fmaf(v, W[k * 3 + 0], l0);
        l1 = fmaf(v, W[k * 3 + 1], l1);
        l2 = fmaf(v, W[k * 3 + 2], l2);
    }
    float mx = fmaxf(l0, fmaxf(l1, l2));
    float e0 = expf(l0 - mx), e1 = expf(l1 - mx), e2 = expf(l2 - mx);
    float lse = logf(e0 + e1 + e2) + mx;
    out[(size_t)i * 3 + 0] = l0 - lse;
    out[(size_t)i * 3 + 1] = l1 - lse;
    out[(size_t)i * 3 + 2] = l2 - lse;
}

// ------------------------------------------------------------------ launch

extern "C" void kernel_launch(void* const* d_in, const int* in_sizes, int n_in,
                              void* d_out, int out_size, void* d_ws, size_t ws_size,
                              hipStream_t stream) {
    const float* x   = (const float*)d_in[0];
    const int* ei    = (const int*)d_in[1];   // int32! (harness converts integer inputs)
    const float* W1l = (const float*)d_in[2];
    const float* b1  = (const float*)d_in[3];
    const float* W1r = (const float*)d_in[4];
    const float* W2l = (const float*)d_in[5];
    const float* b2  = (const float*)d_in[6];
    const float* W2r = (const float*)d_in[7];
    const float* W3l = (const float*)d_in[8];
    const float* b3  = (const float*)d_in[9];
    const float* W3r = (const float*)d_in[10];
    const float* Wl1 = (const float*)d_in[11];
    const float* bl1 = (const float*)d_in[12];
    const float* Wl2 = (const float*)d_in[13];
    const float* bl2 = (const float*)d_in[14];
    const float* Wl3 = (const float*)d_in[15];
    const float* bl3 = (const float*)d_in[16];
    float* out = (float*)d_out;

    const int N = in_sizes[0] / 9;
    const int E = in_sizes[1] / 2;

    char* ws = (char*)d_ws;
    size_t off = 0;
    auto alloc = [&](size_t bytes) -> void* {
        void* p = ws + off;
        off += (bytes + 255) & ~(size_t)255;
        return p;
    };
    float* h_buf   = (float*)alloc((size_t)N * 128 * sizeof(float)); // 51.2 MB
    float* agg_buf = (float*)alloc((size_t)N * 128 * sizeof(float)); // 51.2 MB
    int* rs     = (int*)alloc((size_t)(N + 1) * sizeof(int));
    int* cursor = (int*)alloc((size_t)N * sizeof(int));
    int* deg    = (int*)alloc((size_t)N * sizeof(int));
    int* bsum   = (int*)alloc(512);
    int* boff   = (int*)alloc(512);
    int* csr    = (int*)alloc((size_t)E * sizeof(int));               // 6.4 MB
    (void)ws_size; (void)n_in; (void)out_size;

    const int nb = (N + 1023) / 1024;

    // CSR build (bucket edges by tgt)
    hipMemsetAsync(deg, 0, (size_t)N * sizeof(int), stream);
    hist_k<<<(E + 255) / 256, 256, 0, stream>>>(ei, deg, E);
    scan_block_k<<<nb, 256, 0, stream>>>(deg, rs, bsum, N);
    scan_sums_k<<<1, 64, 0, stream>>>(bsum, boff, nb);
    add_off_k<<<(N + 255) / 256, 256, 0, stream>>>(rs, cursor, boff, N, E);
    fill_k<<<(E + 255) / 256, 256, 0, stream>>>(ei, cursor, csr, E);

    // SAGE layer 1 (9 -> 128)
    agg9_k<<<(N + 255) / 256, 256, 0, stream>>>(x, rs, csr, agg_buf, N);
    lin1_k<<<(N * 128 + 255) / 256, 256, 0, stream>>>(agg_buf, x, W1l, W1r, b1, h_buf, N);

    // SAGE layer 2 (128 -> 128)
    agg128_k<<<(N + 3) / 4, 256, 0, stream>>>(h_buf, rs, csr, agg_buf, N);
    lin_k<128, true, true><<<(N + 63) / 64, 256, 0, stream>>>(
        agg_buf, W2l, 128, h_buf, W2r, 128, b2, h_buf, N);

    // SAGE layer 3 (128 -> 128)
    agg128_k<<<(N + 3) / 4, 256, 0, stream>>>(h_buf, rs, csr, agg_buf, N);
    lin_k<128, true, true><<<(N + 63) / 64, 256, 0, stream>>>(
        agg_buf, W3l, 128, h_buf, W3r, 128, b3, h_buf, N);

    // MLP: 128 -> 128 (relu), 128 -> 64 (relu), 64 -> 3 + log_softmax
    lin_k<128, false, true><<<(N + 63) / 64, 256, 0, stream>>>(
        h_buf, Wl1, 128, nullptr, nullptr, 0, bl1, h_buf, N);
    lin_k<64, false, true><<<(N + 63) / 64, 256, 0, stream>>>(
        h_buf, Wl2, 128, nullptr, nullptr, 0, bl2, agg_buf, N);
    final_k<<<(N + 255) / 256, 256, 0, stream>>>(agg_buf, Wl3, bl3, out, N);
}

// Round 5
// 651.403 us; speedup vs baseline: 1.2082x; 1.2082x over previous
//
#include <hip/hip_runtime.h>
#include <stdint.h>

// ---------------------------------------------------------------- CSR build
// edge_index arrives as int32 (harness converts integer inputs to int32).
//
// R4: deterministic two-level bucket CSR build. The old atomic-scatter fill
// wrote 4B to random lines -> 64B/store writeback (105MB WRITE_SIZE, ~130us).
// Now: bucket edges by t>>SHIFT into contiguous staged runs (coalesced), then
// one block per bucket builds its private csr region (lines written once).

#define CH 16384          // edges per block in bucket passes
#define MAXNB 1024        // max bucket count supported by LDS arrays

__global__ __launch_bounds__(256) void bhist_k(const int* __restrict__ ei,
        int* __restrict__ bh, int E, int shift, int NB, int NBLK) {
    __shared__ int lh[MAXNB];
    for (int b = threadIdx.x; b < NB; b += 256) lh[b] = 0;
    __syncthreads();
    int base = blockIdx.x * CH;
    int end = min(base + CH, E);
    for (int e = base + threadIdx.x; e < end; e += 256) {
        int t = ei[(size_t)E + e];
        atomicAdd(&lh[t >> shift], 1);
    }
    __syncthreads();
    for (int b = threadIdx.x; b < NB; b += 256)
        bh[(size_t)b * NBLK + blockIdx.x] = lh[b];   // column-major per bucket
}

// Exclusive scan of each bucket's per-block counts (NBLK <= 128).
__global__ void scan_col_k(int* bh, int* __restrict__ btot, int NBLK, int NB) {
    __shared__ int sd[128];
    int b = blockIdx.x;
    int t = threadIdx.x;
    int v = (t < NBLK) ? bh[(size_t)b * NBLK + t] : 0;
    sd[t] = v;
    __syncthreads();
    for (int off = 1; off < 128; off <<= 1) {
        int x = (t >= off) ? sd[t - off] : 0;
        __syncthreads();
        sd[t] += x;
        __syncthreads();
    }
    if (t < NBLK) bh[(size_t)b * NBLK + t] = sd[t] - v;   // exclusive
    if (t == 127) btot[b] = sd[127];
}

// Generic single-level exclusive scan (<=1024 elems/block), also used for btot.
__global__ void scan_block_k(const int* __restrict__ deg, int* __restrict__ excl,
                             int* __restrict__ bsum, int N) {
    __shared__ int sd[256];
    int t = threadIdx.x;
    int base = blockIdx.x * 1024 + t * 4;
    int v0 = (base + 0 < N) ? deg[base + 0] : 0;
    int v1 = (base + 1 < N) ? deg[base + 1] : 0;
    int v2 = (base + 2 < N) ? deg[base + 2] : 0;
    int v3 = (base + 3 < N) ? deg[base + 3] : 0;
    int s = v0 + v1 + v2 + v3;
    sd[t] = s;
    __syncthreads();
    for (int off = 1; off < 256; off <<= 1) {
        int x = (t >= off) ? sd[t - off] : 0;
        __syncthreads();
        sd[t] += x;
        __syncthreads();
    }
    int incl = sd[t];
    int ex = incl - s;
    if (base + 0 < N) excl[base + 0] = ex;
    if (base + 1 < N) excl[base + 1] = ex + v0;
    if (base + 2 < N) excl[base + 2] = ex + v0 + v1;
    if (base + 3 < N) excl[base + 3] = ex + v0 + v1 + v2;
    if (t == 255) bsum[blockIdx.x] = incl;
}

// Scatter edges into bucket-contiguous staged runs: staged[p] = s | (lt<<17).
// (s < 2^17 for N=100K; lt = t & (2^shift - 1) fits 7 bits at shift=7.)
__global__ __launch_bounds__(256) void bscatter_k(const int* __restrict__ ei,
        const int* __restrict__ bh, const int* __restrict__ bbase,
        int* __restrict__ staged, int E, int shift, int NB, int NBLK) {
    __shared__ int cur[MAXNB];
    for (int b = threadIdx.x; b < NB; b += 256)
        cur[b] = bbase[b] + bh[(size_t)b * NBLK + blockIdx.x];
    __syncthreads();
    int base = blockIdx.x * CH;
    int end = min(base + CH, E);
    int mask = (1 << shift) - 1;
    for (int e = base + threadIdx.x; e < end; e += 256) {
        int s = ei[e];
        int t = ei[(size_t)E + e];
        int p = atomicAdd(&cur[t >> shift], 1);
        staged[p] = s | ((t & mask) << 17);
    }
}

// One block per bucket: count local targets, scan -> rs (coalesced write),
// then rank-scatter srcs into this bucket's private csr region (stays in L2).
__global__ __launch_bounds__(256) void csrfill_k(const int* __restrict__ staged,
        const int* __restrict__ bbase, int* __restrict__ rs, int* __restrict__ csr,
        int N, int E, int shift, int NB) {
    __shared__ int lh[256];
    __shared__ int sd[256];
    int b = blockIdx.x;
    int tpb = 1 << shift;                 // targets per bucket (<=256)
    int t0 = b << shift;
    int s0 = bbase[b];
    int s1 = (b == NB - 1) ? E : bbase[b + 1];
    int t = threadIdx.x;
    if (t < tpb) lh[t] = 0;
    __syncthreads();
    for (int e = s0 + t; e < s1; e += 256)
        atomicAdd(&lh[staged[e] >> 17], 1);
    __syncthreads();
    int v = (t < tpb) ? lh[t] : 0;
    sd[t] = v;
    __syncthreads();
    for (int off = 1; off < 256; off <<= 1) {
        int x = (t >= off) ? sd[t - off] : 0;
        __syncthreads();
        sd[t] += x;
        __syncthreads();
    }
    if (t < tpb) {
        int excl = sd[t] - v;
        lh[t] = excl;                      // reuse as local cursor
        int tg = t0 + t;
        if (tg < N) rs[tg] = s0 + excl;
    }
    if (b == NB - 1 && t == 0) rs[N] = E;
    __syncthreads();
    for (int e = s0 + t; e < s1; e += 256) {
        int w = staged[e];
        int lt = w >> 17;
        int src = w & 0x1FFFF;
        int p = s0 + atomicAdd(&lh[lt], 1);
        csr[p] = src;
    }
}

// ------------------------------------------------------------- aggregation

// Layer-1 aggregation, F=9: one thread per node.
__global__ void agg9_k(const float* __restrict__ x, const int* __restrict__ rs,
                       const int* __restrict__ csr, float* __restrict__ agg, int N) {
    int i = blockIdx.x * blockDim.x + threadIdx.x;
    if (i >= N) return;
    int s0 = rs[i], s1 = rs[i + 1];
    float a[9];
    #pragma unroll
    for (int f = 0; f < 9; ++f) a[f] = 0.f;
    for (int j = s0; j < s1; ++j) {
        const float* p = x + (size_t)csr[j] * 9;
        #pragma unroll
        for (int f = 0; f < 9; ++f) a[f] += p[f];
    }
    float inv = (s1 > s0) ? 1.f / (float)(s1 - s0) : 0.f;
    float* o = agg + (size_t)i * 9;
    #pragma unroll
    for (int f = 0; f < 9; ++f) o[f] = a[f] * inv;
}

// F=128 aggregation: one wave per node, float2 per lane (512B/row in 1 instr).
__global__ __launch_bounds__(256) void agg128_k(const float* __restrict__ h,
        const int* __restrict__ rs, const int* __restrict__ csr,
        float* __restrict__ out, int N) {
    int lane = threadIdx.x & 63;
    int node = blockIdx.x * 4 + (threadIdx.x >> 6);
    if (node >= N) return;
    int s0 = rs[node], s1 = rs[node + 1];
    const float2* h2 = reinterpret_cast<const float2*>(h);
    float ax = 0.f, ay = 0.f;
    int j = s0;
    for (; j + 4 <= s1; j += 4) {
        int n0 = csr[j], n1 = csr[j + 1], n2 = csr[j + 2], n3 = csr[j + 3];
        float2 v0 = h2[(size_t)n0 * 64 + lane];
        float2 v1 = h2[(size_t)n1 * 64 + lane];
        float2 v2 = h2[(size_t)n2 * 64 + lane];
        float2 v3 = h2[(size_t)n3 * 64 + lane];
        ax += (v0.x + v1.x) + (v2.x + v3.x);
        ay += (v0.y + v1.y) + (v2.y + v3.y);
    }
    for (; j < s1; ++j) {
        float2 v = h2[(size_t)csr[j] * 64 + lane];
        ax += v.x;
        ay += v.y;
    }
    float inv = (s1 > s0) ? 1.f / (float)(s1 - s0) : 0.f;
    float2 r;
    r.x = ax * inv;
    r.y = ay * inv;
    reinterpret_cast<float2*>(out)[(size_t)node * 64 + lane] = r;
}

// ------------------------------------------------------------------- GEMMs

// Layer-1 linear: K=9, out = relu(agg@Wl + x@Wr + b). One thread per (node,col).
__global__ void lin1_k(const float* __restrict__ agg, const float* __restrict__ x,
                       const float* __restrict__ Wl, const float* __restrict__ Wr,
                       const float* __restrict__ b, float* __restrict__ out, int N) {
    int idx = blockIdx.x * blockDim.x + threadIdx.x;
    if (idx >= N * 128) return;
    int i = idx >> 7, c = idx & 127;
    float acc = b[c];
    const float* ar = agg + (size_t)i * 9;
    const float* xr = x + (size_t)i * 9;
    #pragma unroll
    for (int k = 0; k < 9; ++k)
        acc += ar[k] * Wl[k * 128 + c] + xr[k] * Wr[k * 128 + c];
    out[idx] = fmaxf(acc, 0.f);
}

// Tiled fp32 GEMM: C[M,TN] = act(A1@W1 (+ A2@W2) + bias).
// TM=64 rows/block, full output width per block (TN=128 or 64), K multiple of 32.
// NOTE: A/C intentionally NOT __restrict__ — several calls are row-wise in-place.
template<int TN, bool DUAL, bool RELU>
__global__ __launch_bounds__(256) void lin_k(
        const float* A1, const float* __restrict__ W1, int K1,
        const float* A2, const float* __restrict__ W2, int K2,
        const float* __restrict__ bias, float* C, int M) {
    constexpr int TM = 64;
    constexpr int TCOLS = TN / 4;        // 32 or 16
    constexpr int TROWS = 256 / TCOLS;   // 8 or 16
    constexpr int RPT = TM / TROWS;      // 8 or 4 rows per thread
    constexpr int NS = DUAL ? 2 : 1;

    __shared__ float a_lds[TM][36];      // stride 36 floats = 144B (16B multiple)
    __shared__ float w_lds[32][TN];

    int tid = threadIdx.x;
    int tc = tid % TCOLS;
    int tr = tid / TCOLS;
    int rb = blockIdx.x * TM;

    float4 bv = *reinterpret_cast<const float4*>(bias + tc * 4);
    float acc[RPT][4];
    #pragma unroll
    for (int m = 0; m < RPT; ++m) {
        acc[m][0] = bv.x; acc[m][1] = bv.y; acc[m][2] = bv.z; acc[m][3] = bv.w;
    }

    const float* As[2] = {A1, A2};
    const float* Ws[2] = {W1, W2};
    int Ks[2] = {K1, K2};

    for (int s = 0; s < NS; ++s) {
        const float* A = As[s];
        const float* W = Ws[s];
        const int K = Ks[s];
        for (int kt = 0; kt < K; kt += 32) {
            __syncthreads();
            {   // stage A tile: 64 rows x 32 cols, float4 coalesced
                int c4 = (tid & 7) * 4;
                int r = tid >> 3;
                #pragma unroll
                for (int i = 0; i < 2; ++i) {
                    int rr = r + i * 32;
                    int grow = rb + rr;
                    float4 v = make_float4(0.f, 0.f, 0.f, 0.f);
                    if (grow < M)
                        v = *reinterpret_cast<const float4*>(A + (size_t)grow * K + kt + c4);
                    *reinterpret_cast<float4*>(&a_lds[rr][c4]) = v;
                }
            }
            {   // stage W tile: 32 rows x TN cols, float4 coalesced
                constexpr int ITER = (32 * TN) / 1024;
                #pragma unroll
                for (int i = 0; i < ITER; ++i) {
                    int lin4 = (tid + i * 256) * 4;
                    int r = lin4 / TN;
                    int c = lin4 % TN;
                    *reinterpret_cast<float4*>(&w_lds[r][c]) =
                        *reinterpret_cast<const float4*>(W + (size_t)(kt + r) * TN + c);
                }
            }
            __syncthreads();
            #pragma unroll
            for (int k = 0; k < 32; ++k) {
                float4 wv = *reinterpret_cast<const float4*>(&w_lds[k][tc * 4]);
                #pragma unroll
                for (int m = 0; m < RPT; ++m) {
                    float a = a_lds[tr * RPT + m][k];
                    acc[m][0] = fmaf(a, wv.x, acc[m][0]);
                    acc[m][1] = fmaf(a, wv.y, acc[m][1]);
                    acc[m][2] = fmaf(a, wv.z, acc[m][2]);
                    acc[m][3] = fmaf(a, wv.w, acc[m][3]);
                }
            }
        }
    }
    #pragma unroll
    for (int m = 0; m < RPT; ++m) {
        int grow = rb + tr * RPT + m;
        if (grow < M) {
            float4 v;
            v.x = acc[m][0]; v.y = acc[m][1]; v.z = acc[m][2]; v.w = acc[m][3];
            if (RELU) {
                v.x = fmaxf(v.x, 0.f); v.y = fmaxf(v.y, 0.f);
                v.z = fmaxf(v.z, 0.f); v.w = fmaxf(v.w, 0.f);
            }
            *reinterpret_cast<float4*>(C + (size_t)grow * TN + tc * 4) = v;
        }
    }
}

// Final: [N,64] @ [64,3] + b, then log_softmax. One thread per node.
__global__ void final_k(const float* __restrict__ m2, const float* __restrict__ W,
                        const float* __restrict__ b, float* __restrict__ out, int N) {
    int i = blockIdx.x * blockDim.x + threadIdx.x;
    if (i >= N) return;
    const float* r = m2 + (size_t)i * 64;
    float l0 = b[0], l1 = b[1], l2 = b[2];
    #pragma unroll 8
    for (int k = 0; k < 64; ++k) {
        float v = r[k];
        l0 = fmaf(v, W[k * 3 + 0], l0);
        l1 = fmaf(v, W[k * 3 + 1], l1);
        l2 = fmaf(v, W[k * 3 + 2], l2);
    }
    float mx = fmaxf(l0, fmaxf(l1, l2));
    float e0 = expf(l0 - mx), e1 = expf(l1 - mx), e2 = expf(l2 - mx);
    float lse = logf(e0 + e1 + e2) + mx;
    out[(size_t)i * 3 + 0] = l0 - lse;
    out[(size_t)i * 3 + 1] = l1 - lse;
    out[(size_t)i * 3 + 2] = l2 - lse;
}

// ------------------------------------------------------------------ launch

extern "C" void kernel_launch(void* const* d_in, const int* in_sizes, int n_in,
                              void* d_out, int out_size, void* d_ws, size_t ws_size,
                              hipStream_t stream) {
    const float* x   = (const float*)d_in[0];
    const int* ei    = (const int*)d_in[1];   // int32 (harness-converted)
    const float* W1l = (const float*)d_in[2];
    const float* b1  = (const float*)d_in[3];
    const float* W1r = (const float*)d_in[4];
    const float* W2l = (const float*)d_in[5];
    const float* b2  = (const float*)d_in[6];
    const float* W2r = (const float*)d_in[7];
    const float* W3l = (const float*)d_in[8];
    const float* b3  = (const float*)d_in[9];
    const float* W3r = (const float*)d_in[10];
    const float* Wl1 = (const float*)d_in[11];
    const float* bl1 = (const float*)d_in[12];
    const float* Wl2 = (const float*)d_in[13];
    const float* bl2 = (const float*)d_in[14];
    const float* Wl3 = (const float*)d_in[15];
    const float* bl3 = (const float*)d_in[16];
    float* out = (float*)d_out;

    const int N = in_sizes[0] / 9;
    const int E = in_sizes[1] / 2;

    char* ws = (char*)d_ws;
    size_t off = 0;
    auto alloc = [&](size_t bytes) -> void* {
        void* p = ws + off;
        off += (bytes + 255) & ~(size_t)255;
        return p;
    };
    float* h_buf   = (float*)alloc((size_t)N * 128 * sizeof(float)); // 51.2 MB
    float* agg_buf = (float*)alloc((size_t)N * 128 * sizeof(float)); // 51.2 MB
    int* rs     = (int*)alloc((size_t)(N + 1) * sizeof(int));
    int* csr    = (int*)alloc((size_t)E * sizeof(int));               // 6.4 MB
    int* staged = (int*)alloc((size_t)E * sizeof(int));               // 6.4 MB
    (void)ws_size; (void)n_in; (void)out_size;

    // bucket params (N=100K, E=1.6M -> shift=7, NB=782, NBLK=98)
    int shift = 7;
    while ((((size_t)N + ((size_t)1 << shift) - 1) >> shift) > MAXNB) ++shift;
    const int NB = (N + (1 << shift) - 1) >> shift;
    const int NBLK = (E + CH - 1) / CH;               // must be <= 128
    int* bh    = (int*)alloc((size_t)NB * NBLK * sizeof(int));        // 306 KB
    int* btot  = (int*)alloc((size_t)NB * sizeof(int));
    int* bbase = (int*)alloc((size_t)(NB + 1) * sizeof(int));
    int* bsum  = (int*)alloc(64 * sizeof(int));

    // CSR build (two-level bucket, no global-atomic scatter)
    bhist_k<<<NBLK, 256, 0, stream>>>(ei, bh, E, shift, NB, NBLK);
    scan_col_k<<<NB, 128, 0, stream>>>(bh, btot, NBLK, NB);
    scan_block_k<<<1, 256, 0, stream>>>(btot, bbase, bsum, NB);
    bscatter_k<<<NBLK, 256, 0, stream>>>(ei, bh, bbase, staged, E, shift, NB, NBLK);
    csrfill_k<<<NB, 256, 0, stream>>>(staged, bbase, rs, csr, N, E, shift, NB);

    // SAGE layer 1 (9 -> 128)
    agg9_k<<<(N + 255) / 256, 256, 0, stream>>>(x, rs, csr, agg_buf, N);
    lin1_k<<<(N * 128 + 255) / 256, 256, 0, stream>>>(agg_buf, x, W1l, W1r, b1, h_buf, N);

    // SAGE layer 2 (128 -> 128)
    agg128_k<<<(N + 3) / 4, 256, 0, stream>>>(h_buf, rs, csr, agg_buf, N);
    lin_k<128, true, true><<<(N + 63) / 64, 256, 0, stream>>>(
        agg_buf, W2l, 128, h_buf, W2r, 128, b2, h_buf, N);

    // SAGE layer 3 (128 -> 128)
    agg128_k<<<(N + 3) / 4, 256, 0, stream>>>(h_buf, rs, csr, agg_buf, N);
    lin_k<128, true, true><<<(N + 63) / 64, 256, 0, stream>>>(
        agg_buf, W3l, 128, h_buf, W3r, 128, b3, h_buf, N);

    // MLP: 128 -> 128 (relu), 128 -> 64 (relu), 64 -> 3 + log_softmax
    lin_k<128, false, true><<<(N + 63) / 64, 256, 0, stream>>>(
        h_buf, Wl1, 128, nullptr, nullptr, 0, bl1, h_buf, N);
    lin_k<64, false, true><<<(N + 63) / 64, 256, 0, stream>>>(
        h_buf, Wl2, 128, nullptr, nullptr, 0, bl2, agg_buf, N);
    final_k<<<(N + 255) / 256, 256, 0, stream>>>(agg_buf, Wl3, bl3, out, N);
}

// Round 6
// 573.873 us; speedup vs baseline: 1.3714x; 1.1351x over previous
//
#include <hip/hip_runtime.h>
#include <hip/hip_fp16.h>
#include <stdint.h>

// ---------------------------------------------------------------- CSR build
// edge_index arrives as int32 (harness converts integer inputs to int32).
// R4: deterministic two-level bucket CSR build (no global-atomic scatter;
// csr lines written once -> WRITE_SIZE 105MB -> ~17MB, fill_k 130us -> gone).

#define CH 16384          // edges per block in bucket passes
#define MAXNB 1024        // max bucket count supported by LDS arrays

__global__ __launch_bounds__(256) void bhist_k(const int* __restrict__ ei,
        int* __restrict__ bh, int E, int shift, int NB, int NBLK) {
    __shared__ int lh[MAXNB];
    for (int b = threadIdx.x; b < NB; b += 256) lh[b] = 0;
    __syncthreads();
    int base = blockIdx.x * CH;
    int end = min(base + CH, E);
    for (int e = base + threadIdx.x; e < end; e += 256) {
        int t = ei[(size_t)E + e];
        atomicAdd(&lh[t >> shift], 1);
    }
    __syncthreads();
    for (int b = threadIdx.x; b < NB; b += 256)
        bh[(size_t)b * NBLK + blockIdx.x] = lh[b];   // column-major per bucket
}

// Exclusive scan of each bucket's per-block counts (NBLK <= 128).
__global__ void scan_col_k(int* bh, int* __restrict__ btot, int NBLK, int NB) {
    __shared__ int sd[128];
    int b = blockIdx.x;
    int t = threadIdx.x;
    int v = (t < NBLK) ? bh[(size_t)b * NBLK + t] : 0;
    sd[t] = v;
    __syncthreads();
    for (int off = 1; off < 128; off <<= 1) {
        int x = (t >= off) ? sd[t - off] : 0;
        __syncthreads();
        sd[t] += x;
        __syncthreads();
    }
    if (t < NBLK) bh[(size_t)b * NBLK + t] = sd[t] - v;   // exclusive
    if (t == 127) btot[b] = sd[127];
}

// Generic single-level exclusive scan (<=1024 elems/block), used for btot.
__global__ void scan_block_k(const int* __restrict__ deg, int* __restrict__ excl,
                             int* __restrict__ bsum, int N) {
    __shared__ int sd[256];
    int t = threadIdx.x;
    int base = blockIdx.x * 1024 + t * 4;
    int v0 = (base + 0 < N) ? deg[base + 0] : 0;
    int v1 = (base + 1 < N) ? deg[base + 1] : 0;
    int v2 = (base + 2 < N) ? deg[base + 2] : 0;
    int v3 = (base + 3 < N) ? deg[base + 3] : 0;
    int s = v0 + v1 + v2 + v3;
    sd[t] = s;
    __syncthreads();
    for (int off = 1; off < 256; off <<= 1) {
        int x = (t >= off) ? sd[t - off] : 0;
        __syncthreads();
        sd[t] += x;
        __syncthreads();
    }
    int incl = sd[t];
    int ex = incl - s;
    if (base + 0 < N) excl[base + 0] = ex;
    if (base + 1 < N) excl[base + 1] = ex + v0;
    if (base + 2 < N) excl[base + 2] = ex + v0 + v1;
    if (base + 3 < N) excl[base + 3] = ex + v0 + v1 + v2;
    if (t == 255) bsum[blockIdx.x] = incl;
}

// Scatter edges into bucket-contiguous staged runs: staged[p] = s | (lt<<17).
__global__ __launch_bounds__(256) void bscatter_k(const int* __restrict__ ei,
        const int* __restrict__ bh, const int* __restrict__ bbase,
        int* __restrict__ staged, int E, int shift, int NB, int NBLK) {
    __shared__ int cur[MAXNB];
    for (int b = threadIdx.x; b < NB; b += 256)
        cur[b] = bbase[b] + bh[(size_t)b * NBLK + blockIdx.x];
    __syncthreads();
    int base = blockIdx.x * CH;
    int end = min(base + CH, E);
    int mask = (1 << shift) - 1;
    for (int e = base + threadIdx.x; e < end; e += 256) {
        int s = ei[e];
        int t = ei[(size_t)E + e];
        int p = atomicAdd(&cur[t >> shift], 1);
        staged[p] = s | ((t & mask) << 17);
    }
}

// One block per bucket: count local targets, scan -> rs, rank-scatter srcs
// into this bucket's private csr region (stays in one L2, written once).
__global__ __launch_bounds__(256) void csrfill_k(const int* __restrict__ staged,
        const int* __restrict__ bbase, int* __restrict__ rs, int* __restrict__ csr,
        int N, int E, int shift, int NB) {
    __shared__ int lh[256];
    __shared__ int sd[256];
    int b = blockIdx.x;
    int tpb = 1 << shift;                 // targets per bucket (<=256)
    int t0 = b << shift;
    int s0 = bbase[b];
    int s1 = (b == NB - 1) ? E : bbase[b + 1];
    int t = threadIdx.x;
    if (t < tpb) lh[t] = 0;
    __syncthreads();
    for (int e = s0 + t; e < s1; e += 256)
        atomicAdd(&lh[staged[e] >> 17], 1);
    __syncthreads();
    int v = (t < tpb) ? lh[t] : 0;
    sd[t] = v;
    __syncthreads();
    for (int off = 1; off < 256; off <<= 1) {
        int x = (t >= off) ? sd[t - off] : 0;
        __syncthreads();
        sd[t] += x;
        __syncthreads();
    }
    if (t < tpb) {
        int excl = sd[t] - v;
        lh[t] = excl;                      // reuse as local cursor
        int tg = t0 + t;
        if (tg < N) rs[tg] = s0 + excl;
    }
    if (b == NB - 1 && t == 0) rs[N] = E;
    __syncthreads();
    for (int e = s0 + t; e < s1; e += 256) {
        int w = staged[e];
        int lt = w >> 17;
        int src = w & 0x1FFFF;
        int p = s0 + atomicAdd(&lh[lt], 1);
        csr[p] = src;
    }
}

// ------------------------------------------------------------- aggregation

// Layer-1 aggregation, F=9: one thread per node.
__global__ void agg9_k(const float* __restrict__ x, const int* __restrict__ rs,
                       const int* __restrict__ csr, float* __restrict__ agg, int N) {
    int i = blockIdx.x * blockDim.x + threadIdx.x;
    if (i >= N) return;
    int s0 = rs[i], s1 = rs[i + 1];
    float a[9];
    #pragma unroll
    for (int f = 0; f < 9; ++f) a[f] = 0.f;
    for (int j = s0; j < s1; ++j) {
        const float* p = x + (size_t)csr[j] * 9;
        #pragma unroll
        for (int f = 0; f < 9; ++f) a[f] += p[f];
    }
    float inv = (s1 > s0) ? 1.f / (float)(s1 - s0) : 0.f;
    float* o = agg + (size_t)i * 9;
    #pragma unroll
    for (int f = 0; f < 9; ++f) o[f] = a[f] * inv;
}

// F=128 aggregation from the fp16 mirror of h: one wave per node.
// R5: gathers were byte-volume bound (377MB FETCH, 112us). fp16 halves the
// per-edge payload (512B -> 256B row, half2/lane); 8-deep edge unroll keeps
// in-flight bytes ~constant. fp32 accumulate; fp16 rel-err 2^-12 is safe.
__global__ __launch_bounds__(256) void agg128h_k(const __half* __restrict__ h16,
        const int* __restrict__ rs, const int* __restrict__ csr,
        float* __restrict__ out, int N) {
    int lane = threadIdx.x & 63;
    int node = blockIdx.x * 4 + (threadIdx.x >> 6);
    if (node >= N) return;
    int s0 = rs[node], s1 = rs[node + 1];
    const __half2* h2 = reinterpret_cast<const __half2*>(h16);   // N x 64 half2
    float ax = 0.f, ay = 0.f;
    int j = s0;
    for (; j + 8 <= s1; j += 8) {
        int n[8];
        #pragma unroll
        for (int u = 0; u < 8; ++u) n[u] = csr[j + u];
        float2 v[8];
        #pragma unroll
        for (int u = 0; u < 8; ++u)
            v[u] = __half22float2(h2[(size_t)n[u] * 64 + lane]);
        #pragma unroll
        for (int u = 0; u < 8; ++u) { ax += v[u].x; ay += v[u].y; }
    }
    for (; j < s1; ++j) {
        float2 v = __half22float2(h2[(size_t)csr[j] * 64 + lane]);
        ax += v.x; ay += v.y;
    }
    float inv = (s1 > s0) ? 1.f / (float)(s1 - s0) : 0.f;
    float2 r;
    r.x = ax * inv;
    r.y = ay * inv;
    reinterpret_cast<float2*>(out)[(size_t)node * 64 + lane] = r;
}

// ------------------------------------------------------------------- GEMMs

// Layer-1 linear: K=9, out = relu(agg@Wl + x@Wr + b), plus fp16 mirror.
__global__ void lin1_k(const float* __restrict__ agg, const float* __restrict__ x,
                       const float* __restrict__ Wl, const float* __restrict__ Wr,
                       const float* __restrict__ b, float* __restrict__ out,
                       __half* __restrict__ out16, int N) {
    int idx = blockIdx.x * blockDim.x + threadIdx.x;
    if (idx >= N * 128) return;
    int i = idx >> 7, c = idx & 127;
    float acc = b[c];
    const float* ar = agg + (size_t)i * 9;
    const float* xr = x + (size_t)i * 9;
    #pragma unroll
    for (int k = 0; k < 9; ++k)
        acc += ar[k] * Wl[k * 128 + c] + xr[k] * Wr[k * 128 + c];
    float v = fmaxf(acc, 0.f);
    out[idx] = v;
    out16[idx] = __float2half_rn(v);
}

// Tiled fp32 GEMM: C[M,TN] = act(A1@W1 (+ A2@W2) + bias), optional fp16 mirror.
// TM=64 rows/block, full output width per block (TN=128 or 64), K multiple of 32.
// NOTE: A/C intentionally NOT __restrict__ — several calls are row-wise in-place.
template<int TN, bool DUAL, bool RELU, bool H16>
__global__ __launch_bounds__(256) void lin_k(
        const float* A1, const float* __restrict__ W1, int K1,
        const float* A2, const float* __restrict__ W2, int K2,
        const float* __restrict__ bias, float* C, __half* C16, int M) {
    constexpr int TM = 64;
    constexpr int TCOLS = TN / 4;        // 32 or 16
    constexpr int TROWS = 256 / TCOLS;   // 8 or 16
    constexpr int RPT = TM / TROWS;      // 8 or 4 rows per thread
    constexpr int NS = DUAL ? 2 : 1;

    __shared__ float a_lds[TM][36];      // stride 36 floats = 144B (16B multiple)
    __shared__ float w_lds[32][TN];

    int tid = threadIdx.x;
    int tc = tid % TCOLS;
    int tr = tid / TCOLS;
    int rb = blockIdx.x * TM;

    float4 bv = *reinterpret_cast<const float4*>(bias + tc * 4);
    float acc[RPT][4];
    #pragma unroll
    for (int m = 0; m < RPT; ++m) {
        acc[m][0] = bv.x; acc[m][1] = bv.y; acc[m][2] = bv.z; acc[m][3] = bv.w;
    }

    const float* As[2] = {A1, A2};
    const float* Ws[2] = {W1, W2};
    int Ks[2] = {K1, K2};

    for (int s = 0; s < NS; ++s) {
        const float* A = As[s];
        const float* W = Ws[s];
        const int K = Ks[s];
        for (int kt = 0; kt < K; kt += 32) {
            __syncthreads();
            {   // stage A tile: 64 rows x 32 cols, float4 coalesced
                int c4 = (tid & 7) * 4;
                int r = tid >> 3;
                #pragma unroll
                for (int i = 0; i < 2; ++i) {
                    int rr = r + i * 32;
                    int grow = rb + rr;
                    float4 v = make_float4(0.f, 0.f, 0.f, 0.f);
                    if (grow < M)
                        v = *reinterpret_cast<const float4*>(A + (size_t)grow * K + kt + c4);
                    *reinterpret_cast<float4*>(&a_lds[rr][c4]) = v;
                }
            }
            {   // stage W tile: 32 rows x TN cols, float4 coalesced
                constexpr int ITER = (32 * TN) / 1024;
                #pragma unroll
                for (int i = 0; i < ITER; ++i) {
                    int lin4 = (tid + i * 256) * 4;
                    int r = lin4 / TN;
                    int c = lin4 % TN;
                    *reinterpret_cast<float4*>(&w_lds[r][c]) =
                        *reinterpret_cast<const float4*>(W + (size_t)(kt + r) * TN + c);
                }
            }
            __syncthreads();
            #pragma unroll
            for (int k = 0; k < 32; ++k) {
                float4 wv = *reinterpret_cast<const float4*>(&w_lds[k][tc * 4]);
                #pragma unroll
                for (int m = 0; m < RPT; ++m) {
                    float a = a_lds[tr * RPT + m][k];
                    acc[m][0] = fmaf(a, wv.x, acc[m][0]);
                    acc[m][1] = fmaf(a, wv.y, acc[m][1]);
                    acc[m][2] = fmaf(a, wv.z, acc[m][2]);
                    acc[m][3] = fmaf(a, wv.w, acc[m][3]);
                }
            }
        }
    }
    #pragma unroll
    for (int m = 0; m < RPT; ++m) {
        int grow = rb + tr * RPT + m;
        if (grow < M) {
            float4 v;
            v.x = acc[m][0]; v.y = acc[m][1]; v.z = acc[m][2]; v.w = acc[m][3];
            if (RELU) {
                v.x = fmaxf(v.x, 0.f); v.y = fmaxf(v.y, 0.f);
                v.z = fmaxf(v.z, 0.f); v.w = fmaxf(v.w, 0.f);
            }
            *reinterpret_cast<float4*>(C + (size_t)grow * TN + tc * 4) = v;
            if (H16) {
                __half2 p0 = __floats2half2_rn(v.x, v.y);
                __half2 p1 = __floats2half2_rn(v.z, v.w);
                uint2 pk;
                pk.x = *reinterpret_cast<unsigned int*>(&p0);
                pk.y = *reinterpret_cast<unsigned int*>(&p1);
                *reinterpret_cast<uint2*>(C16 + (size_t)grow * TN + tc * 4) = pk;
            }
        }
    }
}

// Final: [N,64] @ [64,3] + b, then log_softmax. One thread per node.
__global__ void final_k(const float* __restrict__ m2, const float* __restrict__ W,
                        const float* __restrict__ b, float* __restrict__ out, int N) {
    int i = blockIdx.x * blockDim.x + threadIdx.x;
    if (i >= N) return;
    const float* r = m2 + (size_t)i * 64;
    float l0 = b[0], l1 = b[1], l2 = b[2];
    #pragma unroll 8
    for (int k = 0; k < 64; ++k) {
        float v = r[k];
        l0 = fmaf(v, W[k * 3 + 0], l0);
        l1 = fmaf(v, W[k * 3 + 1], l1);
        l2 = fmaf(v, W[k * 3 + 2], l2);
    }
    float mx = fmaxf(l0, fmaxf(l1, l2));
    float e0 = expf(l0 - mx), e1 = expf(l1 - mx), e2 = expf(l2 - mx);
    float lse = logf(e0 + e1 + e2) + mx;
    out[(size_t)i * 3 + 0] = l0 - lse;
    out[(size_t)i * 3 + 1] = l1 - lse;
    out[(size_t)i * 3 + 2] = l2 - lse;
}

// ------------------------------------------------------------------ launch

extern "C" void kernel_launch(void* const* d_in, const int* in_sizes, int n_in,
                              void* d_out, int out_size, void* d_ws, size_t ws_size,
                              hipStream_t stream) {
    const float* x   = (const float*)d_in[0];
    const int* ei    = (const int*)d_in[1];   // int32 (harness-converted)
    const float* W1l = (const float*)d_in[2];
    const float* b1  = (const float*)d_in[3];
    const float* W1r = (const float*)d_in[4];
    const float* W2l = (const float*)d_in[5];
    const float* b2  = (const float*)d_in[6];
    const float* W2r = (const float*)d_in[7];
    const float* W3l = (const float*)d_in[8];
    const float* b3  = (const float*)d_in[9];
    const float* W3r = (const float*)d_in[10];
    const float* Wl1 = (const float*)d_in[11];
    const float* bl1 = (const float*)d_in[12];
    const float* Wl2 = (const float*)d_in[13];
    const float* bl2 = (const float*)d_in[14];
    const float* Wl3 = (const float*)d_in[15];
    const float* bl3 = (const float*)d_in[16];
    float* out = (float*)d_out;

    const int N = in_sizes[0] / 9;
    const int E = in_sizes[1] / 2;

    char* ws = (char*)d_ws;
    size_t off = 0;
    auto alloc = [&](size_t bytes) -> void* {
        void* p = ws + off;
        off += (bytes + 255) & ~(size_t)255;
        return p;
    };
    float* h_buf   = (float*)alloc((size_t)N * 128 * sizeof(float));  // 51.2 MB
    float* agg_buf = (float*)alloc((size_t)N * 128 * sizeof(float));  // 51.2 MB
    __half* h16    = (__half*)alloc((size_t)N * 128 * sizeof(__half)); // 25.6 MB
    int* rs     = (int*)alloc((size_t)(N + 1) * sizeof(int));
    int* csr    = (int*)alloc((size_t)E * sizeof(int));                // 6.4 MB
    int* staged = (int*)alloc((size_t)E * sizeof(int));                // 6.4 MB
    (void)ws_size; (void)n_in; (void)out_size;

    // bucket params (N=100K, E=1.6M -> shift=7, NB=782, NBLK=98)
    int shift = 7;
    while ((((size_t)N + ((size_t)1 << shift) - 1) >> shift) > MAXNB) ++shift;
    const int NB = (N + (1 << shift) - 1) >> shift;
    const int NBLK = (E + CH - 1) / CH;               // must be <= 128
    int* bh    = (int*)alloc((size_t)NB * NBLK * sizeof(int));
    int* btot  = (int*)alloc((size_t)NB * sizeof(int));
    int* bbase = (int*)alloc((size_t)(NB + 1) * sizeof(int));
    int* bsum  = (int*)alloc(64 * sizeof(int));

    // CSR build (two-level bucket, no global-atomic scatter)
    bhist_k<<<NBLK, 256, 0, stream>>>(ei, bh, E, shift, NB, NBLK);
    scan_col_k<<<NB, 128, 0, stream>>>(bh, btot, NBLK, NB);
    scan_block_k<<<1, 256, 0, stream>>>(btot, bbase, bsum, NB);
    bscatter_k<<<NBLK, 256, 0, stream>>>(ei, bh, bbase, staged, E, shift, NB, NBLK);
    csrfill_k<<<NB, 256, 0, stream>>>(staged, bbase, rs, csr, N, E, shift, NB);

    // SAGE layer 1 (9 -> 128): h1 (+ fp16 mirror)
    agg9_k<<<(N + 255) / 256, 256, 0, stream>>>(x, rs, csr, agg_buf, N);
    lin1_k<<<(N * 128 + 255) / 256, 256, 0, stream>>>(agg_buf, x, W1l, W1r, b1,
                                                      h_buf, h16, N);

    // SAGE layer 2 (128 -> 128): gather fp16 h1, dual GEMM -> h2 (+ mirror)
    agg128h_k<<<(N + 3) / 4, 256, 0, stream>>>(h16, rs, csr, agg_buf, N);
    lin_k<128, true, true, true><<<(N + 63) / 64, 256, 0, stream>>>(
        agg_buf, W2l, 128, h_buf, W2r, 128, b2, h_buf, h16, N);

    // SAGE layer 3 (128 -> 128): gather fp16 h2, dual GEMM -> h3 (no mirror)
    agg128h_k<<<(N + 3) / 4, 256, 0, stream>>>(h16, rs, csr, agg_buf, N);
    lin_k<128, true, true, false><<<(N + 63) / 64, 256, 0, stream>>>(
        agg_buf, W3l, 128, h_buf, W3r, 128, b3, h_buf, nullptr, N);

    // MLP: 128 -> 128 (relu), 128 -> 64 (relu), 64 -> 3 + log_softmax
    lin_k<128, false, true, false><<<(N + 63) / 64, 256, 0, stream>>>(
        h_buf, Wl1, 128, nullptr, nullptr, 0, bl1, h_buf, nullptr, N);
    lin_k<64, false, true, false><<<(N + 63) / 64, 256, 0, stream>>>(
        h_buf, Wl2, 128, nullptr, nullptr, 0, bl2, agg_buf, nullptr, N);
    final_k<<<(N + 255) / 256, 256, 0, stream>>>(agg_buf, Wl3, bl3, out, N);
}

// Round 7
// 385.991 us; speedup vs baseline: 2.0389x; 1.4868x over previous
//
#include <hip/hip_runtime.h>
#include <hip/hip_fp16.h>
#include <stdint.h>

typedef _Float16 f16x8 __attribute__((ext_vector_type(8)));
typedef float f32x4 __attribute__((ext_vector_type(4)));

// ---------------------------------------------------------------- CSR build
// edge_index arrives as int32 (harness converts integer inputs to int32).
// R4: deterministic two-level bucket CSR build (no global-atomic scatter).

#define CH 16384          // edges per block in bucket passes
#define MAXNB 1024        // max bucket count supported by LDS arrays

__global__ __launch_bounds__(256) void bhist_k(const int* __restrict__ ei,
        int* __restrict__ bh, int E, int shift, int NB, int NBLK) {
    __shared__ int lh[MAXNB];
    for (int b = threadIdx.x; b < NB; b += 256) lh[b] = 0;
    __syncthreads();
    int base = blockIdx.x * CH;
    int end = min(base + CH, E);
    for (int e = base + threadIdx.x; e < end; e += 256) {
        int t = ei[(size_t)E + e];
        atomicAdd(&lh[t >> shift], 1);
    }
    __syncthreads();
    for (int b = threadIdx.x; b < NB; b += 256)
        bh[(size_t)b * NBLK + blockIdx.x] = lh[b];   // column-major per bucket
}

__global__ void scan_col_k(int* bh, int* __restrict__ btot, int NBLK, int NB) {
    __shared__ int sd[128];
    int b = blockIdx.x;
    int t = threadIdx.x;
    int v = (t < NBLK) ? bh[(size_t)b * NBLK + t] : 0;
    sd[t] = v;
    __syncthreads();
    for (int off = 1; off < 128; off <<= 1) {
        int x = (t >= off) ? sd[t - off] : 0;
        __syncthreads();
        sd[t] += x;
        __syncthreads();
    }
    if (t < NBLK) bh[(size_t)b * NBLK + t] = sd[t] - v;   // exclusive
    if (t == 127) btot[b] = sd[127];
}

__global__ void scan_block_k(const int* __restrict__ deg, int* __restrict__ excl,
                             int* __restrict__ bsum, int N) {
    __shared__ int sd[256];
    int t = threadIdx.x;
    int base = blockIdx.x * 1024 + t * 4;
    int v0 = (base + 0 < N) ? deg[base + 0] : 0;
    int v1 = (base + 1 < N) ? deg[base + 1] : 0;
    int v2 = (base + 2 < N) ? deg[base + 2] : 0;
    int v3 = (base + 3 < N) ? deg[base + 3] : 0;
    int s = v0 + v1 + v2 + v3;
    sd[t] = s;
    __syncthreads();
    for (int off = 1; off < 256; off <<= 1) {
        int x = (t >= off) ? sd[t - off] : 0;
        __syncthreads();
        sd[t] += x;
        __syncthreads();
    }
    int incl = sd[t];
    int ex = incl - s;
    if (base + 0 < N) excl[base + 0] = ex;
    if (base + 1 < N) excl[base + 1] = ex + v0;
    if (base + 2 < N) excl[base + 2] = ex + v0 + v1;
    if (base + 3 < N) excl[base + 3] = ex + v0 + v1 + v2;
    if (t == 255) bsum[blockIdx.x] = incl;
}

__global__ __launch_bounds__(256) void bscatter_k(const int* __restrict__ ei,
        const int* __restrict__ bh, const int* __restrict__ bbase,
        int* __restrict__ staged, int E, int shift, int NB, int NBLK) {
    __shared__ int cur[MAXNB];
    for (int b = threadIdx.x; b < NB; b += 256)
        cur[b] = bbase[b] + bh[(size_t)b * NBLK + blockIdx.x];
    __syncthreads();
    int base = blockIdx.x * CH;
    int end = min(base + CH, E);
    int mask = (1 << shift) - 1;
    for (int e = base + threadIdx.x; e < end; e += 256) {
        int s = ei[e];
        int t = ei[(size_t)E + e];
        int p = atomicAdd(&cur[t >> shift], 1);
        staged[p] = s | ((t & mask) << 17);
    }
}

__global__ __launch_bounds__(256) void csrfill_k(const int* __restrict__ staged,
        const int* __restrict__ bbase, int* __restrict__ rs, int* __restrict__ csr,
        int N, int E, int shift, int NB) {
    __shared__ int lh[256];
    __shared__ int sd[256];
    int b = blockIdx.x;
    int tpb = 1 << shift;                 // targets per bucket (<=256)
    int t0 = b << shift;
    int s0 = bbase[b];
    int s1 = (b == NB - 1) ? E : bbase[b + 1];
    int t = threadIdx.x;
    if (t < tpb) lh[t] = 0;
    __syncthreads();
    for (int e = s0 + t; e < s1; e += 256)
        atomicAdd(&lh[staged[e] >> 17], 1);
    __syncthreads();
    int v = (t < tpb) ? lh[t] : 0;
    sd[t] = v;
    __syncthreads();
    for (int off = 1; off < 256; off <<= 1) {
        int x = (t >= off) ? sd[t - off] : 0;
        __syncthreads();
        sd[t] += x;
        __syncthreads();
    }
    if (t < tpb) {
        int excl = sd[t] - v;
        lh[t] = excl;                      // reuse as local cursor
        int tg = t0 + t;
        if (tg < N) rs[tg] = s0 + excl;
    }
    if (b == NB - 1 && t == 0) rs[N] = E;
    __syncthreads();
    for (int e = s0 + t; e < s1; e += 256) {
        int w = staged[e];
        int lt = w >> 17;
        int src = w & 0x1FFFF;
        int p = s0 + atomicAdd(&lh[lt], 1);
        csr[p] = src;
    }
}

// ------------------------------------------------------------- aggregation

// Layer-1 aggregation, F=9: one thread per node (fp32, tiny).
__global__ void agg9_k(const float* __restrict__ x, const int* __restrict__ rs,
                       const int* __restrict__ csr, float* __restrict__ agg, int N) {
    int i = blockIdx.x * blockDim.x + threadIdx.x;
    if (i >= N) return;
    int s0 = rs[i], s1 = rs[i + 1];
    float a[9];
    #pragma unroll
    for (int f = 0; f < 9; ++f) a[f] = 0.f;
    for (int j = s0; j < s1; ++j) {
        const float* p = x + (size_t)csr[j] * 9;
        #pragma unroll
        for (int f = 0; f < 9; ++f) a[f] += p[f];
    }
    float inv = (s1 > s0) ? 1.f / (float)(s1 - s0) : 0.f;
    float* o = agg + (size_t)i * 9;
    #pragma unroll
    for (int f = 0; f < 9; ++f) o[f] = a[f] * inv;
}

// F=128 aggregation from fp16 h: one wave per node, half2/lane, fp32 accum.
// R7: output fp16 directly (feeds the MFMA GEMM; also halves WRITE_SIZE).
__global__ __launch_bounds__(256) void agg128h_k(const __half* __restrict__ h16,
        const int* __restrict__ rs, const int* __restrict__ csr,
        __half2* __restrict__ out, int N) {
    int lane = threadIdx.x & 63;
    int node = blockIdx.x * 4 + (threadIdx.x >> 6);
    if (node >= N) return;
    int s0 = rs[node], s1 = rs[node + 1];
    const __half2* h2 = reinterpret_cast<const __half2*>(h16);   // N x 64 half2
    float ax = 0.f, ay = 0.f;
    int j = s0;
    for (; j + 8 <= s1; j += 8) {
        int n[8];
        #pragma unroll
        for (int u = 0; u < 8; ++u) n[u] = csr[j + u];
        float2 v[8];
        #pragma unroll
        for (int u = 0; u < 8; ++u)
            v[u] = __half22float2(h2[(size_t)n[u] * 64 + lane]);
        #pragma unroll
        for (int u = 0; u < 8; ++u) { ax += v[u].x; ay += v[u].y; }
    }
    for (; j < s1; ++j) {
        float2 v = __half22float2(h2[(size_t)csr[j] * 64 + lane]);
        ax += v.x; ay += v.y;
    }
    float inv = (s1 > s0) ? 1.f / (float)(s1 - s0) : 0.f;
    out[(size_t)node * 64 + lane] = __floats2half2_rn(ax * inv, ay * inv);
}

// ------------------------------------------------------------------- GEMMs

// Layer-1 linear: K=9, h1 = relu(agg@Wl + x@Wr + b) -> fp16.
__global__ void lin1_k(const float* __restrict__ agg, const float* __restrict__ x,
                       const float* __restrict__ Wl, const float* __restrict__ Wr,
                       const float* __restrict__ b, __half* __restrict__ out16, int N) {
    int idx = blockIdx.x * blockDim.x + threadIdx.x;
    if (idx >= N * 128) return;
    int i = idx >> 7, c = idx & 127;
    float acc = b[c];
    const float* ar = agg + (size_t)i * 9;
    const float* xr = x + (size_t)i * 9;
    #pragma unroll
    for (int k = 0; k < 9; ++k)
        acc += ar[k] * Wl[k * 128 + c] + xr[k] * Wr[k * 128 + c];
    out16[idx] = __float2half_rn(fmaxf(acc, 0.f));
}

// Pack fp32 W[K][N] into MFMA B-fragment order, fp16:
// frag (nf, kb): lane l holds B[kb*32 + (l>>4)*8 + j][nf*16 + (l&15)], j=0..7,
// stored contiguously at ((nf*(K/32)+kb)*64 + l)*8.  (m89/m92-verified layout)
__global__ void wpack_k(const float* __restrict__ W, _Float16* __restrict__ wpk,
                        int K, int N) {
    int idx = blockIdx.x * blockDim.x + threadIdx.x;
    int total = (N / 16) * (K / 32) * 64;
    if (idx >= total) return;
    int lane = idx & 63;
    int blk = idx >> 6;
    int kcb = K / 32;
    int kb = blk % kcb;
    int nf = blk / kcb;
    int col = nf * 16 + (lane & 15);
    int k0 = kb * 32 + (lane >> 4) * 8;
    f16x8 v;
    #pragma unroll
    for (int j = 0; j < 8; ++j)
        v[j] = (_Float16)W[(size_t)(k0 + j) * N + col];
    *reinterpret_cast<f16x8*>(wpk + (size_t)idx * 8) = v;
}

// MFMA fp16 GEMM: C[M,TN] = relu(A1@W1 (+ A2@W2) + bias), fp32 accum, fp16 out.
// K=128 fixed. Block: 64 rows x TN cols, 4 waves; wave owns NF 16-col frags.
// A staged in LDS (+8-half pad -> 2-way bank conflict = free, m136);
// B frags are 16B/lane loads from packed weights (L2-resident).
// A-frag: row=lane&15, k=(lane>>4)*8+[0,8); C/D: col=lane&15, row=(lane>>4)*4+reg.
// Row-wise in-place (C == A1 or A2) is safe: block reads only its own rows
// during staging, writes them only in the epilogue.
template<int NF, bool DUAL>
__global__ __launch_bounds__(256) void mfma_lin_k(
        const __half* A1, const __half* A2,
        const _Float16* __restrict__ pk1, const _Float16* __restrict__ pk2,
        const float* __restrict__ bias, __half* C, int M) {
    constexpr int NS = DUAL ? 2 : 1;
    constexpr int TN = 64 * NF;          // 128 or 64
    constexpr int K = 128;
    __shared__ _Float16 a_lds[NS][64][136];

    int tid = threadIdx.x;
    int lane = tid & 63;
    int wave = tid >> 6;
    int rb = blockIdx.x * 64;

    const __half* As[2] = {A1, A2};
    #pragma unroll
    for (int s = 0; s < NS; ++s) {
        #pragma unroll
        for (int i = 0; i < 4; ++i) {
            int row = (tid >> 4) + i * 16;
            int grow = rb + row;
            uint4 v = make_uint4(0, 0, 0, 0);
            if (grow < M)
                v = reinterpret_cast<const uint4*>(As[s] + (size_t)grow * K)[tid & 15];
            *reinterpret_cast<uint4*>(&a_lds[s][row][(tid & 15) * 8]) = v;
        }
    }

    const _Float16* pks[2] = {pk1, pk2};
    f16x8 bfrag[NS][4][NF];
    #pragma unroll
    for (int s = 0; s < NS; ++s)
        #pragma unroll
        for (int kb = 0; kb < 4; ++kb)
            #pragma unroll
            for (int n = 0; n < NF; ++n) {
                int nf = wave * NF + n;
                bfrag[s][kb][n] =
                    reinterpret_cast<const f16x8*>(pks[s])[(size_t)(nf * 4 + kb) * 64 + lane];
            }

    f32x4 acc[4][NF];
    #pragma unroll
    for (int m = 0; m < 4; ++m)
        #pragma unroll
        for (int n = 0; n < NF; ++n)
            acc[m][n] = (f32x4){0.f, 0.f, 0.f, 0.f};

    __syncthreads();

    #pragma unroll
    for (int s = 0; s < NS; ++s)
        #pragma unroll
        for (int kb = 0; kb < 4; ++kb)
            #pragma unroll
            for (int m = 0; m < 4; ++m) {
                f16x8 a = *reinterpret_cast<const f16x8*>(
                    &a_lds[s][m * 16 + (lane & 15)][kb * 32 + (lane >> 4) * 8]);
                #pragma unroll
                for (int n = 0; n < NF; ++n)
                    acc[m][n] = __builtin_amdgcn_mfma_f32_16x16x32_f16(
                        a, bfrag[s][kb][n], acc[m][n], 0, 0, 0);
            }

    #pragma unroll
    for (int n = 0; n < NF; ++n) {
        int col = wave * NF * 16 + n * 16 + (lane & 15);
        float bv = bias[col];
        #pragma unroll
        for (int m = 0; m < 4; ++m) {
            #pragma unroll
            for (int j = 0; j < 4; ++j) {
                int grow = rb + m * 16 + (lane >> 4) * 4 + j;
                if (grow < M) {
                    float v = fmaxf(acc[m][n][j] + bv, 0.f);
                    C[(size_t)grow * TN + col] = __float2half_rn(v);
                }
            }
        }
    }
}

// Final: [N,64] fp16 @ [64,3] fp32 + b, then log_softmax. One thread per node.
__global__ void final_k(const __half* __restrict__ m2, const float* __restrict__ W,
                        const float* __restrict__ b, float* __restrict__ out, int N) {
    int i = blockIdx.x * blockDim.x + threadIdx.x;
    if (i >= N) return;
    const f16x8* r8 = reinterpret_cast<const f16x8*>(m2 + (size_t)i * 64);
    float l0 = b[0], l1 = b[1], l2 = b[2];
    #pragma unroll
    for (int q = 0; q < 8; ++q) {
        f16x8 v8 = r8[q];
        #pragma unroll
        for (int j = 0; j < 8; ++j) {
            float v = (float)v8[j];
            int k = q * 8 + j;
            l0 = fmaf(v, W[k * 3 + 0], l0);
            l1 = fmaf(v, W[k * 3 + 1], l1);
            l2 = fmaf(v, W[k * 3 + 2], l2);
        }
    }
    float mx = fmaxf(l0, fmaxf(l1, l2));
    float e0 = expf(l0 - mx), e1 = expf(l1 - mx), e2 = expf(l2 - mx);
    float lse = logf(e0 + e1 + e2) + mx;
    out[(size_t)i * 3 + 0] = l0 - lse;
    out[(size_t)i * 3 + 1] = l1 - lse;
    out[(size_t)i * 3 + 2] = l2 - lse;
}

// ------------------------------------------------------------------ launch

extern "C" void kernel_launch(void* const* d_in, const int* in_sizes, int n_in,
                              void* d_out, int out_size, void* d_ws, size_t ws_size,
                              hipStream_t stream) {
    const float* x   = (const float*)d_in[0];
    const int* ei    = (const int*)d_in[1];   // int32 (harness-converted)
    const float* W1l = (const float*)d_in[2];
    const float* b1  = (const float*)d_in[3];
    const float* W1r = (const float*)d_in[4];
    const float* W2l = (const float*)d_in[5];
    const float* b2  = (const float*)d_in[6];
    const float* W2r = (const float*)d_in[7];
    const float* W3l = (const float*)d_in[8];
    const float* b3  = (const float*)d_in[9];
    const float* W3r = (const float*)d_in[10];
    const float* Wl1 = (const float*)d_in[11];
    const float* bl1 = (const float*)d_in[12];
    const float* Wl2 = (const float*)d_in[13];
    const float* bl2 = (const float*)d_in[14];
    const float* Wl3 = (const float*)d_in[15];
    const float* bl3 = (const float*)d_in[16];
    float* out = (float*)d_out;

    const int N = in_sizes[0] / 9;
    const int E = in_sizes[1] / 2;

    char* ws = (char*)d_ws;
    size_t off = 0;
    auto alloc = [&](size_t bytes) -> void* {
        void* p = ws + off;
        off += (bytes + 255) & ~(size_t)255;
        return p;
    };
    __half* h16    = (__half*)alloc((size_t)N * 128 * sizeof(__half));  // 25.6 MB
    __half* agg16  = (__half*)alloc((size_t)N * 128 * sizeof(__half));  // 25.6 MB
    __half* m16    = (__half*)alloc((size_t)N * 64 * sizeof(__half));   // 12.8 MB
    float* agg9buf = (float*)alloc((size_t)N * 9 * sizeof(float));      // 3.6 MB
    int* rs     = (int*)alloc((size_t)(N + 1) * sizeof(int));
    int* csr    = (int*)alloc((size_t)E * sizeof(int));                  // 6.4 MB
    int* staged = (int*)alloc((size_t)E * sizeof(int));                  // 6.4 MB
    _Float16* wpk2l = (_Float16*)alloc(128 * 128 * sizeof(_Float16));
    _Float16* wpk2r = (_Float16*)alloc(128 * 128 * sizeof(_Float16));
    _Float16* wpk3l = (_Float16*)alloc(128 * 128 * sizeof(_Float16));
    _Float16* wpk3r = (_Float16*)alloc(128 * 128 * sizeof(_Float16));
    _Float16* wpkl1 = (_Float16*)alloc(128 * 128 * sizeof(_Float16));
    _Float16* wpkl2 = (_Float16*)alloc(128 * 64 * sizeof(_Float16));
    (void)ws_size; (void)n_in; (void)out_size;

    // bucket params (N=100K, E=1.6M -> shift=7, NB=782, NBLK=98)
    int shift = 7;
    while ((((size_t)N + ((size_t)1 << shift) - 1) >> shift) > MAXNB) ++shift;
    const int NB = (N + (1 << shift) - 1) >> shift;
    const int NBLK = (E + CH - 1) / CH;               // must be <= 128
    int* bh    = (int*)alloc((size_t)NB * NBLK * sizeof(int));
    int* btot  = (int*)alloc((size_t)NB * sizeof(int));
    int* bbase = (int*)alloc((size_t)(NB + 1) * sizeof(int));
    int* bsum  = (int*)alloc(64 * sizeof(int));

    // Weight packing (tiny; independent of CSR build)
    wpack_k<<<8, 256, 0, stream>>>(W2l, wpk2l, 128, 128);
    wpack_k<<<8, 256, 0, stream>>>(W2r, wpk2r, 128, 128);
    wpack_k<<<8, 256, 0, stream>>>(W3l, wpk3l, 128, 128);
    wpack_k<<<8, 256, 0, stream>>>(W3r, wpk3r, 128, 128);
    wpack_k<<<8, 256, 0, stream>>>(Wl1, wpkl1, 128, 128);
    wpack_k<<<4, 256, 0, stream>>>(Wl2, wpkl2, 128, 64);

    // CSR build (two-level bucket, no global-atomic scatter)
    bhist_k<<<NBLK, 256, 0, stream>>>(ei, bh, E, shift, NB, NBLK);
    scan_col_k<<<NB, 128, 0, stream>>>(bh, btot, NBLK, NB);
    scan_block_k<<<1, 256, 0, stream>>>(btot, bbase, bsum, NB);
    bscatter_k<<<NBLK, 256, 0, stream>>>(ei, bh, bbase, staged, E, shift, NB, NBLK);
    csrfill_k<<<NB, 256, 0, stream>>>(staged, bbase, rs, csr, N, E, shift, NB);

    const int gemm_grid = (N + 63) / 64;

    // SAGE layer 1 (9 -> 128): h1 fp16
    agg9_k<<<(N + 255) / 256, 256, 0, stream>>>(x, rs, csr, agg9buf, N);
    lin1_k<<<(N * 128 + 255) / 256, 256, 0, stream>>>(agg9buf, x, W1l, W1r, b1, h16, N);

    // SAGE layer 2 (128 -> 128): gather h1 -> agg16; h2 = relu(agg@W2l + h1@W2r + b2)
    agg128h_k<<<(N + 3) / 4, 256, 0, stream>>>(h16, rs, csr, (__half2*)agg16, N);
    mfma_lin_k<2, true><<<gemm_grid, 256, 0, stream>>>(
        agg16, h16, wpk2l, wpk2r, b2, h16, N);

    // SAGE layer 3 (128 -> 128)
    agg128h_k<<<(N + 3) / 4, 256, 0, stream>>>(h16, rs, csr, (__half2*)agg16, N);
    mfma_lin_k<2, true><<<gemm_grid, 256, 0, stream>>>(
        agg16, h16, wpk3l, wpk3r, b3, h16, N);

    // MLP: 128 -> 128 (relu), 128 -> 64 (relu), 64 -> 3 + log_softmax
    mfma_lin_k<2, false><<<gemm_grid, 256, 0, stream>>>(
        h16, nullptr, wpkl1, nullptr, bl1, h16, N);
    mfma_lin_k<1, false><<<gemm_grid, 256, 0, stream>>>(
        h16, nullptr, wpkl2, nullptr, bl2, m16, N);
    final_k<<<(N + 255) / 256, 256, 0, stream>>>(m16, Wl3, bl3, out, N);
}

// Round 8
// 360.117 us; speedup vs baseline: 2.1854x; 1.0718x over previous
//
#include <hip/hip_runtime.h>
#include <hip/hip_fp16.h>
#include <stdint.h>

typedef _Float16 f16x8 __attribute__((ext_vector_type(8)));
typedef float f32x4 __attribute__((ext_vector_type(4)));

// ---------------------------------------------------------------- CSR build
// edge_index arrives as int32 (harness converts integer inputs to int32).
// R4: deterministic two-level bucket CSR build (no global-atomic scatter).

#define CH 16384          // edges per block in bucket passes
#define MAXNB 1024        // max bucket count supported by LDS arrays

__global__ __launch_bounds__(256) void bhist_k(const int* __restrict__ ei,
        int* __restrict__ bh, int E, int shift, int NB, int NBLK) {
    __shared__ int lh[MAXNB];
    for (int b = threadIdx.x; b < NB; b += 256) lh[b] = 0;
    __syncthreads();
    int base = blockIdx.x * CH;
    int end = min(base + CH, E);
    for (int e = base + threadIdx.x; e < end; e += 256) {
        int t = ei[(size_t)E + e];
        atomicAdd(&lh[t >> shift], 1);
    }
    __syncthreads();
    for (int b = threadIdx.x; b < NB; b += 256)
        bh[(size_t)b * NBLK + blockIdx.x] = lh[b];   // column-major per bucket
}

__global__ void scan_col_k(int* bh, int* __restrict__ btot, int NBLK, int NB) {
    __shared__ int sd[128];
    int b = blockIdx.x;
    int t = threadIdx.x;
    int v = (t < NBLK) ? bh[(size_t)b * NBLK + t] : 0;
    sd[t] = v;
    __syncthreads();
    for (int off = 1; off < 128; off <<= 1) {
        int x = (t >= off) ? sd[t - off] : 0;
        __syncthreads();
        sd[t] += x;
        __syncthreads();
    }
    if (t < NBLK) bh[(size_t)b * NBLK + t] = sd[t] - v;   // exclusive
    if (t == 127) btot[b] = sd[127];
}

__global__ void scan_block_k(const int* __restrict__ deg, int* __restrict__ excl,
                             int* __restrict__ bsum, int N) {
    __shared__ int sd[256];
    int t = threadIdx.x;
    int base = blockIdx.x * 1024 + t * 4;
    int v0 = (base + 0 < N) ? deg[base + 0] : 0;
    int v1 = (base + 1 < N) ? deg[base + 1] : 0;
    int v2 = (base + 2 < N) ? deg[base + 2] : 0;
    int v3 = (base + 3 < N) ? deg[base + 3] : 0;
    int s = v0 + v1 + v2 + v3;
    sd[t] = s;
    __syncthreads();
    for (int off = 1; off < 256; off <<= 1) {
        int x = (t >= off) ? sd[t - off] : 0;
        __syncthreads();
        sd[t] += x;
        __syncthreads();
    }
    int incl = sd[t];
    int ex = incl - s;
    if (base + 0 < N) excl[base + 0] = ex;
    if (base + 1 < N) excl[base + 1] = ex + v0;
    if (base + 2 < N) excl[base + 2] = ex + v0 + v1;
    if (base + 3 < N) excl[base + 3] = ex + v0 + v1 + v2;
    if (t == 255) bsum[blockIdx.x] = incl;
}

__global__ __launch_bounds__(256) void bscatter_k(const int* __restrict__ ei,
        const int* __restrict__ bh, const int* __restrict__ bbase,
        int* __restrict__ staged, int E, int shift, int NB, int NBLK) {
    __shared__ int cur[MAXNB];
    for (int b = threadIdx.x; b < NB; b += 256)
        cur[b] = bbase[b] + bh[(size_t)b * NBLK + blockIdx.x];
    __syncthreads();
    int base = blockIdx.x * CH;
    int end = min(base + CH, E);
    int mask = (1 << shift) - 1;
    for (int e = base + threadIdx.x; e < end; e += 256) {
        int s = ei[e];
        int t = ei[(size_t)E + e];
        int p = atomicAdd(&cur[t >> shift], 1);
        staged[p] = s | ((t & mask) << 17);
    }
}

__global__ __launch_bounds__(256) void csrfill_k(const int* __restrict__ staged,
        const int* __restrict__ bbase, int* __restrict__ rs, int* __restrict__ csr,
        int N, int E, int shift, int NB) {
    __shared__ int lh[256];
    __shared__ int sd[256];
    int b = blockIdx.x;
    int tpb = 1 << shift;                 // targets per bucket (<=256)
    int t0 = b << shift;
    int s0 = bbase[b];
    int s1 = (b == NB - 1) ? E : bbase[b + 1];
    int t = threadIdx.x;
    if (t < tpb) lh[t] = 0;
    __syncthreads();
    for (int e = s0 + t; e < s1; e += 256)
        atomicAdd(&lh[staged[e] >> 17], 1);
    __syncthreads();
    int v = (t < tpb) ? lh[t] : 0;
    sd[t] = v;
    __syncthreads();
    for (int off = 1; off < 256; off <<= 1) {
        int x = (t >= off) ? sd[t - off] : 0;
        __syncthreads();
        sd[t] += x;
        __syncthreads();
    }
    if (t < tpb) {
        int excl = sd[t] - v;
        lh[t] = excl;                      // reuse as local cursor
        int tg = t0 + t;
        if (tg < N) rs[tg] = s0 + excl;
    }
    if (b == NB - 1 && t == 0) rs[N] = E;
    __syncthreads();
    for (int e = s0 + t; e < s1; e += 256) {
        int w = staged[e];
        int lt = w >> 17;
        int src = w & 0x1FFFF;
        int p = s0 + atomicAdd(&lh[lt], 1);
        csr[p] = src;
    }
}

// ------------------------------------------------------------- aggregation

// Layer-1 aggregation, F=9: one thread per node (fp32, tiny).
__global__ void agg9_k(const float* __restrict__ x, const int* __restrict__ rs,
                       const int* __restrict__ csr, float* __restrict__ agg, int N) {
    int i = blockIdx.x * blockDim.x + threadIdx.x;
    if (i >= N) return;
    int s0 = rs[i], s1 = rs[i + 1];
    float a[9];
    #pragma unroll
    for (int f = 0; f < 9; ++f) a[f] = 0.f;
    for (int j = s0; j < s1; ++j) {
        const float* p = x + (size_t)csr[j] * 9;
        #pragma unroll
        for (int f = 0; f < 9; ++f) a[f] += p[f];
    }
    float inv = (s1 > s0) ? 1.f / (float)(s1 - s0) : 0.f;
    float* o = agg + (size_t)i * 9;
    #pragma unroll
    for (int f = 0; f < 9; ++f) o[f] = a[f] * inv;
}

// F=128 fp16 aggregation: 4 nodes per wave, 16 lanes per row, uint4 (16B)/lane.
// R8: R7's wave-per-node (256B/instr) was VMEM-issue bound (throughput FELL
// to 5.8 TB/s vs fp32's 7.3). One wave instr now gathers 4 edges x 256B = 1KB
// (the 16B/lane sweet spot) -> ~2.9x fewer VMEM instructions, same bytes.
// Masked lanes (degree variance across the 4 nodes) cost issue, not bytes.
// fp32 accumulate, per-node edge order unchanged -> bitwise-identical output.
__global__ __launch_bounds__(256) void agg128h4_k(const __half* __restrict__ h16,
        const int* __restrict__ rs, const int* __restrict__ csr,
        __half* __restrict__ out, int N) {
    int l16 = threadIdx.x & 15;
    int node = blockIdx.x * 16 + (threadIdx.x >> 4);
    if (node >= N) return;
    int s0 = rs[node], s1 = rs[node + 1];
    const uint4* h4 = reinterpret_cast<const uint4*>(h16);   // N x 16 uint4
    float acc[8];
    #pragma unroll
    for (int c = 0; c < 8; ++c) acc[c] = 0.f;
    int j = s0;
    for (; j + 4 <= s1; j += 4) {
        uint4 v[4];
        #pragma unroll
        for (int u = 0; u < 4; ++u)
            v[u] = h4[(size_t)csr[j + u] * 16 + l16];
        #pragma unroll
        for (int u = 0; u < 4; ++u) {
            const __half2* p = reinterpret_cast<const __half2*>(&v[u]);
            #pragma unroll
            for (int q = 0; q < 4; ++q) {
                float2 f = __half22float2(p[q]);
                acc[q * 2]     += f.x;
                acc[q * 2 + 1] += f.y;
            }
        }
    }
    for (; j < s1; ++j) {
        uint4 vv = h4[(size_t)csr[j] * 16 + l16];
        const __half2* p = reinterpret_cast<const __half2*>(&vv);
        #pragma unroll
        for (int q = 0; q < 4; ++q) {
            float2 f = __half22float2(p[q]);
            acc[q * 2]     += f.x;
            acc[q * 2 + 1] += f.y;
        }
    }
    float inv = (s1 > s0) ? 1.f / (float)(s1 - s0) : 0.f;
    __half2 o[4];
    #pragma unroll
    for (int q = 0; q < 4; ++q)
        o[q] = __floats2half2_rn(acc[q * 2] * inv, acc[q * 2 + 1] * inv);
    reinterpret_cast<uint4*>(out)[(size_t)node * 16 + l16] =
        *reinterpret_cast<uint4*>(o);
}

// ------------------------------------------------------------------- GEMMs

// Layer-1 linear: K=9, h1 = relu(agg@Wl + x@Wr + b) -> fp16.
__global__ void lin1_k(const float* __restrict__ agg, const float* __restrict__ x,
                       const float* __restrict__ Wl, const float* __restrict__ Wr,
                       const float* __restrict__ b, __half* __restrict__ out16, int N) {
    int idx = blockIdx.x * blockDim.x + threadIdx.x;
    if (idx >= N * 128) return;
    int i = idx >> 7, c = idx & 127;
    float acc = b[c];
    const float* ar = agg + (size_t)i * 9;
    const float* xr = x + (size_t)i * 9;
    #pragma unroll
    for (int k = 0; k < 9; ++k)
        acc += ar[k] * Wl[k * 128 + c] + xr[k] * Wr[k * 128 + c];
    out16[idx] = __float2half_rn(fmaxf(acc, 0.f));
}

// Pack fp32 W[K][N] into MFMA B-fragment order, fp16:
// frag (nf, kb): lane l holds B[kb*32 + (l>>4)*8 + j][nf*16 + (l&15)], j=0..7,
// stored contiguously at ((nf*(K/32)+kb)*64 + l)*8.  (m89/m92-verified layout)
__global__ void wpack_k(const float* __restrict__ W, _Float16* __restrict__ wpk,
                        int K, int N) {
    int idx = blockIdx.x * blockDim.x + threadIdx.x;
    int total = (N / 16) * (K / 32) * 64;
    if (idx >= total) return;
    int lane = idx & 63;
    int blk = idx >> 6;
    int kcb = K / 32;
    int kb = blk % kcb;
    int nf = blk / kcb;
    int col = nf * 16 + (lane & 15);
    int k0 = kb * 32 + (lane >> 4) * 8;
    f16x8 v;
    #pragma unroll
    for (int j = 0; j < 8; ++j)
        v[j] = (_Float16)W[(size_t)(k0 + j) * N + col];
    *reinterpret_cast<f16x8*>(wpk + (size_t)idx * 8) = v;
}

// MFMA fp16 GEMM: C[M,TN] = relu(A1@W1 (+ A2@W2) + bias), fp32 accum, fp16 out.
// K=128 fixed. Block: 64 rows x TN cols, 4 waves; wave owns NF 16-col frags.
// Row-wise in-place (C == A1 or A2) is safe.
template<int NF, bool DUAL>
__global__ __launch_bounds__(256) void mfma_lin_k(
        const __half* A1, const __half* A2,
        const _Float16* __restrict__ pk1, const _Float16* __restrict__ pk2,
        const float* __restrict__ bias, __half* C, int M) {
    constexpr int NS = DUAL ? 2 : 1;
    constexpr int TN = 64 * NF;          // 128 or 64
    constexpr int K = 128;
    __shared__ _Float16 a_lds[NS][64][136];

    int tid = threadIdx.x;
    int lane = tid & 63;
    int wave = tid >> 6;
    int rb = blockIdx.x * 64;

    const __half* As[2] = {A1, A2};
    #pragma unroll
    for (int s = 0; s < NS; ++s) {
        #pragma unroll
        for (int i = 0; i < 4; ++i) {
            int row = (tid >> 4) + i * 16;
            int grow = rb + row;
            uint4 v = make_uint4(0, 0, 0, 0);
            if (grow < M)
                v = reinterpret_cast<const uint4*>(As[s] + (size_t)grow * K)[tid & 15];
            *reinterpret_cast<uint4*>(&a_lds[s][row][(tid & 15) * 8]) = v;
        }
    }

    const _Float16* pks[2] = {pk1, pk2};
    f16x8 bfrag[NS][4][NF];
    #pragma unroll
    for (int s = 0; s < NS; ++s)
        #pragma unroll
        for (int kb = 0; kb < 4; ++kb)
            #pragma unroll
            for (int n = 0; n < NF; ++n) {
                int nf = wave * NF + n;
                bfrag[s][kb][n] =
                    reinterpret_cast<const f16x8*>(pks[s])[(size_t)(nf * 4 + kb) * 64 + lane];
            }

    f32x4 acc[4][NF];
    #pragma unroll
    for (int m = 0; m < 4; ++m)
        #pragma unroll
        for (int n = 0; n < NF; ++n)
            acc[m][n] = (f32x4){0.f, 0.f, 0.f, 0.f};

    __syncthreads();

    #pragma unroll
    for (int s = 0; s < NS; ++s)
        #pragma unroll
        for (int kb = 0; kb < 4; ++kb)
            #pragma unroll
            for (int m = 0; m < 4; ++m) {
                f16x8 a = *reinterpret_cast<const f16x8*>(
                    &a_lds[s][m * 16 + (lane & 15)][kb * 32 + (lane >> 4) * 8]);
                #pragma unroll
                for (int n = 0; n < NF; ++n)
                    acc[m][n] = __builtin_amdgcn_mfma_f32_16x16x32_f16(
                        a, bfrag[s][kb][n], acc[m][n], 0, 0, 0);
            }

    #pragma unroll
    for (int n = 0; n < NF; ++n) {
        int col = wave * NF * 16 + n * 16 + (lane & 15);
        float bv = bias[col];
        #pragma unroll
        for (int m = 0; m < 4; ++m) {
            #pragma unroll
            for (int j = 0; j < 4; ++j) {
                int grow = rb + m * 16 + (lane >> 4) * 4 + j;
                if (grow < M) {
                    float v = fmaxf(acc[m][n][j] + bv, 0.f);
                    C[(size_t)grow * TN + col] = __float2half_rn(v);
                }
            }
        }
    }
}

// Final: [N,64] fp16 @ [64,3] fp32 + b, then log_softmax. One thread per node.
__global__ void final_k(const __half* __restrict__ m2, const float* __restrict__ W,
                        const float* __restrict__ b, float* __restrict__ out, int N) {
    int i = blockIdx.x * blockDim.x + threadIdx.x;
    if (i >= N) return;
    const f16x8* r8 = reinterpret_cast<const f16x8*>(m2 + (size_t)i * 64);
    float l0 = b[0], l1 = b[1], l2 = b[2];
    #pragma unroll
    for (int q = 0; q < 8; ++q) {
        f16x8 v8 = r8[q];
        #pragma unroll
        for (int j = 0; j < 8; ++j) {
            float v = (float)v8[j];
            int k = q * 8 + j;
            l0 = fmaf(v, W[k * 3 + 0], l0);
            l1 = fmaf(v, W[k * 3 + 1], l1);
            l2 = fmaf(v, W[k * 3 + 2], l2);
        }
    }
    float mx = fmaxf(l0, fmaxf(l1, l2));
    float e0 = expf(l0 - mx), e1 = expf(l1 - mx), e2 = expf(l2 - mx);
    float lse = logf(e0 + e1 + e2) + mx;
    out[(size_t)i * 3 + 0] = l0 - lse;
    out[(size_t)i * 3 + 1] = l1 - lse;
    out[(size_t)i * 3 + 2] = l2 - lse;
}

// ------------------------------------------------------------------ launch

extern "C" void kernel_launch(void* const* d_in, const int* in_sizes, int n_in,
                              void* d_out, int out_size, void* d_ws, size_t ws_size,
                              hipStream_t stream) {
    const float* x   = (const float*)d_in[0];
    const int* ei    = (const int*)d_in[1];   // int32 (harness-converted)
    const float* W1l = (const float*)d_in[2];
    const float* b1  = (const float*)d_in[3];
    const float* W1r = (const float*)d_in[4];
    const float* W2l = (const float*)d_in[5];
    const float* b2  = (const float*)d_in[6];
    const float* W2r = (const float*)d_in[7];
    const float* W3l = (const float*)d_in[8];
    const float* b3  = (const float*)d_in[9];
    const float* W3r = (const float*)d_in[10];
    const float* Wl1 = (const float*)d_in[11];
    const float* bl1 = (const float*)d_in[12];
    const float* Wl2 = (const float*)d_in[13];
    const float* bl2 = (const float*)d_in[14];
    const float* Wl3 = (const float*)d_in[15];
    const float* bl3 = (const float*)d_in[16];
    float* out = (float*)d_out;

    const int N = in_sizes[0] / 9;
    const int E = in_sizes[1] / 2;

    char* ws = (char*)d_ws;
    size_t off = 0;
    auto alloc = [&](size_t bytes) -> void* {
        void* p = ws + off;
        off += (bytes + 255) & ~(size_t)255;
        return p;
    };
    __half* h16    = (__half*)alloc((size_t)N * 128 * sizeof(__half));  // 25.6 MB
    __half* agg16  = (__half*)alloc((size_t)N * 128 * sizeof(__half));  // 25.6 MB
    __half* m16    = (__half*)alloc((size_t)N * 64 * sizeof(__half));   // 12.8 MB
    float* agg9buf = (float*)alloc((size_t)N * 9 * sizeof(float));      // 3.6 MB
    int* rs     = (int*)alloc((size_t)(N + 1) * sizeof(int));
    int* csr    = (int*)alloc((size_t)E * sizeof(int));                  // 6.4 MB
    int* staged = (int*)alloc((size_t)E * sizeof(int));                  // 6.4 MB
    _Float16* wpk2l = (_Float16*)alloc(128 * 128 * sizeof(_Float16));
    _Float16* wpk2r = (_Float16*)alloc(128 * 128 * sizeof(_Float16));
    _Float16* wpk3l = (_Float16*)alloc(128 * 128 * sizeof(_Float16));
    _Float16* wpk3r = (_Float16*)alloc(128 * 128 * sizeof(_Float16));
    _Float16* wpkl1 = (_Float16*)alloc(128 * 128 * sizeof(_Float16));
    _Float16* wpkl2 = (_Float16*)alloc(128 * 64 * sizeof(_Float16));
    (void)ws_size; (void)n_in; (void)out_size;

    // bucket params (N=100K, E=1.6M -> shift=7, NB=782, NBLK=98)
    int shift = 7;
    while ((((size_t)N + ((size_t)1 << shift) - 1) >> shift) > MAXNB) ++shift;
    const int NB = (N + (1 << shift) - 1) >> shift;
    const int NBLK = (E + CH - 1) / CH;               // must be <= 128
    int* bh    = (int*)alloc((size_t)NB * NBLK * sizeof(int));
    int* btot  = (int*)alloc((size_t)NB * sizeof(int));
    int* bbase = (int*)alloc((size_t)(NB + 1) * sizeof(int));
    int* bsum  = (int*)alloc(64 * sizeof(int));

    // Weight packing (tiny; independent of CSR build)
    wpack_k<<<8, 256, 0, stream>>>(W2l, wpk2l, 128, 128);
    wpack_k<<<8, 256, 0, stream>>>(W2r, wpk2r, 128, 128);
    wpack_k<<<8, 256, 0, stream>>>(W3l, wpk3l, 128, 128);
    wpack_k<<<8, 256, 0, stream>>>(W3r, wpk3r, 128, 128);
    wpack_k<<<8, 256, 0, stream>>>(Wl1, wpkl1, 128, 128);
    wpack_k<<<4, 256, 0, stream>>>(Wl2, wpkl2, 128, 64);

    // CSR build (two-level bucket, no global-atomic scatter)
    bhist_k<<<NBLK, 256, 0, stream>>>(ei, bh, E, shift, NB, NBLK);
    scan_col_k<<<NB, 128, 0, stream>>>(bh, btot, NBLK, NB);
    scan_block_k<<<1, 256, 0, stream>>>(btot, bbase, bsum, NB);
    bscatter_k<<<NBLK, 256, 0, stream>>>(ei, bh, bbase, staged, E, shift, NB, NBLK);
    csrfill_k<<<NB, 256, 0, stream>>>(staged, bbase, rs, csr, N, E, shift, NB);

    const int gemm_grid = (N + 63) / 64;
    const int agg_grid = (N + 15) / 16;

    // SAGE layer 1 (9 -> 128): h1 fp16
    agg9_k<<<(N + 255) / 256, 256, 0, stream>>>(x, rs, csr, agg9buf, N);
    lin1_k<<<(N * 128 + 255) / 256, 256, 0, stream>>>(agg9buf, x, W1l, W1r, b1, h16, N);

    // SAGE layer 2 (128 -> 128): gather h1 -> agg16; h2 = relu(agg@W2l + h1@W2r + b2)
    agg128h4_k<<<agg_grid, 256, 0, stream>>>(h16, rs, csr, agg16, N);
    mfma_lin_k<2, true><<<gemm_grid, 256, 0, stream>>>(
        agg16, h16, wpk2l, wpk2r, b2, h16, N);

    // SAGE layer 3 (128 -> 128)
    agg128h4_k<<<agg_grid, 256, 0, stream>>>(h16, rs, csr, agg16, N);
    mfma_lin_k<2, true><<<gemm_grid, 256, 0, stream>>>(
        agg16, h16, wpk3l, wpk3r, b3, h16, N);

    // MLP: 128 -> 128 (relu), 128 -> 64 (relu), 64 -> 3 + log_softmax
    mfma_lin_k<2, false><<<gemm_grid, 256, 0, stream>>>(
        h16, nullptr, wpkl1, nullptr, bl1, h16, N);
    mfma_lin_k<1, false><<<gemm_grid, 256, 0, stream>>>(
        h16, nullptr, wpkl2, nullptr, bl2, m16, N);
    final_k<<<(N + 255) / 256, 256, 0, stream>>>(m16, Wl3, bl3, out, N);
}

// Round 9
// 320.199 us; speedup vs baseline: 2.4579x; 1.1247x over previous
//
#include <hip/hip_runtime.h>
#include <hip/hip_fp16.h>
#include <stdint.h>

typedef _Float16 f16x8 __attribute__((ext_vector_type(8)));
typedef float f32x4 __attribute__((ext_vector_type(4)));

// ---------------------------------------------------------------- CSR build
// edge_index arrives as int32 (harness converts integer inputs to int32).
// R4: deterministic two-level bucket CSR build (no global-atomic scatter).

#define CH 16384          // edges per block in bucket passes
#define MAXNB 1024        // max bucket count supported by LDS arrays

__global__ __launch_bounds__(256) void bhist_k(const int* __restrict__ ei,
        int* __restrict__ bh, int E, int shift, int NB, int NBLK) {
    __shared__ int lh[MAXNB];
    for (int b = threadIdx.x; b < NB; b += 256) lh[b] = 0;
    __syncthreads();
    int base = blockIdx.x * CH;
    int end = min(base + CH, E);
    for (int e = base + threadIdx.x; e < end; e += 256) {
        int t = ei[(size_t)E + e];
        atomicAdd(&lh[t >> shift], 1);
    }
    __syncthreads();
    for (int b = threadIdx.x; b < NB; b += 256)
        bh[(size_t)b * NBLK + blockIdx.x] = lh[b];   // column-major per bucket
}

__global__ void scan_col_k(int* bh, int* __restrict__ btot, int NBLK, int NB) {
    __shared__ int sd[128];
    int b = blockIdx.x;
    int t = threadIdx.x;
    int v = (t < NBLK) ? bh[(size_t)b * NBLK + t] : 0;
    sd[t] = v;
    __syncthreads();
    for (int off = 1; off < 128; off <<= 1) {
        int x = (t >= off) ? sd[t - off] : 0;
        __syncthreads();
        sd[t] += x;
        __syncthreads();
    }
    if (t < NBLK) bh[(size_t)b * NBLK + t] = sd[t] - v;   // exclusive
    if (t == 127) btot[b] = sd[127];
}

__global__ void scan_block_k(const int* __restrict__ deg, int* __restrict__ excl,
                             int* __restrict__ bsum, int N) {
    __shared__ int sd[256];
    int t = threadIdx.x;
    int base = blockIdx.x * 1024 + t * 4;
    int v0 = (base + 0 < N) ? deg[base + 0] : 0;
    int v1 = (base + 1 < N) ? deg[base + 1] : 0;
    int v2 = (base + 2 < N) ? deg[base + 2] : 0;
    int v3 = (base + 3 < N) ? deg[base + 3] : 0;
    int s = v0 + v1 + v2 + v3;
    sd[t] = s;
    __syncthreads();
    for (int off = 1; off < 256; off <<= 1) {
        int x = (t >= off) ? sd[t - off] : 0;
        __syncthreads();
        sd[t] += x;
        __syncthreads();
    }
    int incl = sd[t];
    int ex = incl - s;
    if (base + 0 < N) excl[base + 0] = ex;
    if (base + 1 < N) excl[base + 1] = ex + v0;
    if (base + 2 < N) excl[base + 2] = ex + v0 + v1;
    if (base + 3 < N) excl[base + 3] = ex + v0 + v1 + v2;
    if (t == 255) bsum[blockIdx.x] = incl;
}

__global__ __launch_bounds__(256) void bscatter_k(const int* __restrict__ ei,
        const int* __restrict__ bh, const int* __restrict__ bbase,
        int* __restrict__ staged, int E, int shift, int NB, int NBLK) {
    __shared__ int cur[MAXNB];
    for (int b = threadIdx.x; b < NB; b += 256)
        cur[b] = bbase[b] + bh[(size_t)b * NBLK + blockIdx.x];
    __syncthreads();
    int base = blockIdx.x * CH;
    int end = min(base + CH, E);
    int mask = (1 << shift) - 1;
    for (int e = base + threadIdx.x; e < end; e += 256) {
        int s = ei[e];
        int t = ei[(size_t)E + e];
        int p = atomicAdd(&cur[t >> shift], 1);
        staged[p] = s | ((t & mask) << 17);
    }
}

__global__ __launch_bounds__(256) void csrfill_k(const int* __restrict__ staged,
        const int* __restrict__ bbase, int* __restrict__ rs, int* __restrict__ csr,
        int N, int E, int shift, int NB) {
    __shared__ int lh[256];
    __shared__ int sd[256];
    int b = blockIdx.x;
    int tpb = 1 << shift;                 // targets per bucket (<=256)
    int t0 = b << shift;
    int s0 = bbase[b];
    int s1 = (b == NB - 1) ? E : bbase[b + 1];
    int t = threadIdx.x;
    if (t < tpb) lh[t] = 0;
    __syncthreads();
    for (int e = s0 + t; e < s1; e += 256)
        atomicAdd(&lh[staged[e] >> 17], 1);
    __syncthreads();
    int v = (t < tpb) ? lh[t] : 0;
    sd[t] = v;
    __syncthreads();
    for (int off = 1; off < 256; off <<= 1) {
        int x = (t >= off) ? sd[t - off] : 0;
        __syncthreads();
        sd[t] += x;
        __syncthreads();
    }
    if (t < tpb) {
        int excl = sd[t] - v;
        lh[t] = excl;                      // reuse as local cursor
        int tg = t0 + t;
        if (tg < N) rs[tg] = s0 + excl;
    }
    if (b == NB - 1 && t == 0) rs[N] = E;
    __syncthreads();
    for (int e = s0 + t; e < s1; e += 256) {
        int w = staged[e];
        int lt = w >> 17;
        int src = w & 0x1FFFF;
        int p = s0 + atomicAdd(&lh[lt], 1);
        csr[p] = src;
    }
}

// ------------------------------------------------------------- aggregation

// Layer-1 aggregation + pack, F=9: one thread per node.
// R9: lin1_k (thread per node,col) was latency-bound on 128x-redundant scalar
// loads (60us, VALUBusy 25%, HBM 7%). Layer 1 now goes through the MFMA GEMM
// as K=32: this kernel emits the padded fp16 A-row [agg9 | x9 | 0...0].
__global__ void agg9pack_k(const float* __restrict__ x, const int* __restrict__ rs,
                           const int* __restrict__ csr, __half* __restrict__ a32,
                           int N) {
    int i = blockIdx.x * blockDim.x + threadIdx.x;
    if (i >= N) return;
    int s0 = rs[i], s1 = rs[i + 1];
    float a[9];
    #pragma unroll
    for (int f = 0; f < 9; ++f) a[f] = 0.f;
    for (int j = s0; j < s1; ++j) {
        const float* p = x + (size_t)csr[j] * 9;
        #pragma unroll
        for (int f = 0; f < 9; ++f) a[f] += p[f];
    }
    float inv = (s1 > s0) ? 1.f / (float)(s1 - s0) : 0.f;
    const float* xr = x + (size_t)i * 9;
    union { _Float16 h[32]; uint4 u4[4]; } o;
    #pragma unroll
    for (int f = 0; f < 9; ++f) o.h[f] = (_Float16)(a[f] * inv);
    #pragma unroll
    for (int f = 0; f < 9; ++f) o.h[9 + f] = (_Float16)xr[f];
    #pragma unroll
    for (int f = 18; f < 32; ++f) o.h[f] = (_Float16)0.f;
    uint4* dst = reinterpret_cast<uint4*>(a32 + (size_t)i * 32);
    #pragma unroll
    for (int q = 0; q < 4; ++q) dst[q] = o.u4[q];
}

// F=128 fp16 aggregation: 4 nodes per wave, 16 lanes per row, uint4 (16B)/lane.
// R8: one wave instr gathers 4 edges x 256B = 1KB (16B/lane sweet spot).
__global__ __launch_bounds__(256) void agg128h4_k(const __half* __restrict__ h16,
        const int* __restrict__ rs, const int* __restrict__ csr,
        __half* __restrict__ out, int N) {
    int l16 = threadIdx.x & 15;
    int node = blockIdx.x * 16 + (threadIdx.x >> 4);
    if (node >= N) return;
    int s0 = rs[node], s1 = rs[node + 1];
    const uint4* h4 = reinterpret_cast<const uint4*>(h16);   // N x 16 uint4
    float acc[8];
    #pragma unroll
    for (int c = 0; c < 8; ++c) acc[c] = 0.f;
    int j = s0;
    for (; j + 4 <= s1; j += 4) {
        uint4 v[4];
        #pragma unroll
        for (int u = 0; u < 4; ++u)
            v[u] = h4[(size_t)csr[j + u] * 16 + l16];
        #pragma unroll
        for (int u = 0; u < 4; ++u) {
            const __half2* p = reinterpret_cast<const __half2*>(&v[u]);
            #pragma unroll
            for (int q = 0; q < 4; ++q) {
                float2 f = __half22float2(p[q]);
                acc[q * 2]     += f.x;
                acc[q * 2 + 1] += f.y;
            }
        }
    }
    for (; j < s1; ++j) {
        uint4 vv = h4[(size_t)csr[j] * 16 + l16];
        const __half2* p = reinterpret_cast<const __half2*>(&vv);
        #pragma unroll
        for (int q = 0; q < 4; ++q) {
            float2 f = __half22float2(p[q]);
            acc[q * 2]     += f.x;
            acc[q * 2 + 1] += f.y;
        }
    }
    float inv = (s1 > s0) ? 1.f / (float)(s1 - s0) : 0.f;
    __half2 o[4];
    #pragma unroll
    for (int q = 0; q < 4; ++q)
        o[q] = __floats2half2_rn(acc[q * 2] * inv, acc[q * 2 + 1] * inv);
    reinterpret_cast<uint4*>(out)[(size_t)node * 16 + l16] =
        *reinterpret_cast<uint4*>(o);
}

// ------------------------------------------------------------------- GEMMs

// Pack fp32 W[K][N] into MFMA B-fragment order, fp16:
// frag (nf, kb): lane l holds B[kb*32 + (l>>4)*8 + j][nf*16 + (l&15)], j=0..7,
// stored contiguously at ((nf*(K/32)+kb)*64 + l)*8.  (m89/m92-verified layout)
__global__ void wpack_k(const float* __restrict__ W, _Float16* __restrict__ wpk,
                        int K, int N) {
    int idx = blockIdx.x * blockDim.x + threadIdx.x;
    int total = (N / 16) * (K / 32) * 64;
    if (idx >= total) return;
    int lane = idx & 63;
    int blk = idx >> 6;
    int kcb = K / 32;
    int kb = blk % kcb;
    int nf = blk / kcb;
    int col = nf * 16 + (lane & 15);
    int k0 = kb * 32 + (lane >> 4) * 8;
    f16x8 v;
    #pragma unroll
    for (int j = 0; j < 8; ++j)
        v[j] = (_Float16)W[(size_t)(k0 + j) * N + col];
    *reinterpret_cast<f16x8*>(wpk + (size_t)idx * 8) = v;
}

// Pack layer-1 combined weight [W1l(9x128); W1r(9x128); 0...] as K=32, N=128.
__global__ void wpack1_k(const float* __restrict__ Wl, const float* __restrict__ Wr,
                         _Float16* __restrict__ wpk) {
    int idx = blockIdx.x * blockDim.x + threadIdx.x;
    if (idx >= 8 * 64) return;               // (N/16=8) * (KB=1) * 64
    int lane = idx & 63;
    int nf = idx >> 6;
    int col = nf * 16 + (lane & 15);
    int k0 = (lane >> 4) * 8;
    f16x8 v;
    #pragma unroll
    for (int j = 0; j < 8; ++j) {
        int k = k0 + j;
        float w = (k < 9) ? Wl[(size_t)k * 128 + col]
                : (k < 18) ? Wr[(size_t)(k - 9) * 128 + col] : 0.f;
        v[j] = (_Float16)w;
    }
    *reinterpret_cast<f16x8*>(wpk + (size_t)idx * 8) = v;
}

// MFMA fp16 GEMM: C[M,TN] = relu(A1@W1 (+ A2@W2) + bias), fp32 accum, fp16 out.
// Block: 64 rows x TN cols, 4 waves; wave owns NF 16-col frags; K = KK.
// Row-wise in-place (C == A1 or A2) is safe.
template<int NF, int NS, int KK>
__global__ __launch_bounds__(256) void mfma_lin_k(
        const __half* A1, const __half* A2,
        const _Float16* __restrict__ pk1, const _Float16* __restrict__ pk2,
        const float* __restrict__ bias, __half* C, int M) {
    constexpr int TN = 64 * NF;          // 128 or 64
    constexpr int KB = KK / 32;
    constexpr int LPR = KK / 8;          // uint4 loads per row
    constexpr int RPI = 256 / LPR;       // rows staged per iteration
    constexpr int ITER = 64 / RPI;
    __shared__ _Float16 a_lds[NS][64][KK + 8];

    int tid = threadIdx.x;
    int lane = tid & 63;
    int wave = tid >> 6;
    int rb = blockIdx.x * 64;

    const __half* As[2] = {A1, A2};
    #pragma unroll
    for (int s = 0; s < NS; ++s) {
        #pragma unroll
        for (int i = 0; i < ITER; ++i) {
            int row = (tid / LPR) + i * RPI;
            int c = tid % LPR;
            int grow = rb + row;
            uint4 v = make_uint4(0, 0, 0, 0);
            if (grow < M)
                v = reinterpret_cast<const uint4*>(As[s] + (size_t)grow * KK)[c];
            *reinterpret_cast<uint4*>(&a_lds[s][row][c * 8]) = v;
        }
    }

    const _Float16* pks[2] = {pk1, pk2};
    f16x8 bfrag[NS][KB][NF];
    #pragma unroll
    for (int s = 0; s < NS; ++s)
        #pragma unroll
        for (int kb = 0; kb < KB; ++kb)
            #pragma unroll
            for (int n = 0; n < NF; ++n) {
                int nf = wave * NF + n;
                bfrag[s][kb][n] =
                    reinterpret_cast<const f16x8*>(pks[s])[(size_t)(nf * KB + kb) * 64 + lane];
            }

    f32x4 acc[4][NF];
    #pragma unroll
    for (int m = 0; m < 4; ++m)
        #pragma unroll
        for (int n = 0; n < NF; ++n)
            acc[m][n] = (f32x4){0.f, 0.f, 0.f, 0.f};

    __syncthreads();

    #pragma unroll
    for (int s = 0; s < NS; ++s)
        #pragma unroll
        for (int kb = 0; kb < KB; ++kb)
            #pragma unroll
            for (int m = 0; m < 4; ++m) {
                f16x8 a = *reinterpret_cast<const f16x8*>(
                    &a_lds[s][m * 16 + (lane & 15)][kb * 32 + (lane >> 4) * 8]);
                #pragma unroll
                for (int n = 0; n < NF; ++n)
                    acc[m][n] = __builtin_amdgcn_mfma_f32_16x16x32_f16(
                        a, bfrag[s][kb][n], acc[m][n], 0, 0, 0);
            }

    #pragma unroll
    for (int n = 0; n < NF; ++n) {
        int col = wave * NF * 16 + n * 16 + (lane & 15);
        float bv = bias[col];
        #pragma unroll
        for (int m = 0; m < 4; ++m) {
            #pragma unroll
            for (int j = 0; j < 4; ++j) {
                int grow = rb + m * 16 + (lane >> 4) * 4 + j;
                if (grow < M) {
                    float v = fmaxf(acc[m][n][j] + bv, 0.f);
                    C[(size_t)grow * TN + col] = __float2half_rn(v);
                }
            }
        }
    }
}

// Final: [N,64] fp16 @ [64,3] fp32 + b, then log_softmax. One thread per node.
__global__ void final_k(const __half* __restrict__ m2, const float* __restrict__ W,
                        const float* __restrict__ b, float* __restrict__ out, int N) {
    int i = blockIdx.x * blockDim.x + threadIdx.x;
    if (i >= N) return;
    const f16x8* r8 = reinterpret_cast<const f16x8*>(m2 + (size_t)i * 64);
    float l0 = b[0], l1 = b[1], l2 = b[2];
    #pragma unroll
    for (int q = 0; q < 8; ++q) {
        f16x8 v8 = r8[q];
        #pragma unroll
        for (int j = 0; j < 8; ++j) {
            float v = (float)v8[j];
            int k = q * 8 + j;
            l0 = fmaf(v, W[k * 3 + 0], l0);
            l1 = fmaf(v, W[k * 3 + 1], l1);
            l2 = fmaf(v, W[k * 3 + 2], l2);
        }
    }
    float mx = fmaxf(l0, fmaxf(l1, l2));
    float e0 = expf(l0 - mx), e1 = expf(l1 - mx), e2 = expf(l2 - mx);
    float lse = logf(e0 + e1 + e2) + mx;
    out[(size_t)i * 3 + 0] = l0 - lse;
    out[(size_t)i * 3 + 1] = l1 - lse;
    out[(size_t)i * 3 + 2] = l2 - lse;
}

// ------------------------------------------------------------------ launch

extern "C" void kernel_launch(void* const* d_in, const int* in_sizes, int n_in,
                              void* d_out, int out_size, void* d_ws, size_t ws_size,
                              hipStream_t stream) {
    const float* x   = (const float*)d_in[0];
    const int* ei    = (const int*)d_in[1];   // int32 (harness-converted)
    const float* W1l = (const float*)d_in[2];
    const float* b1  = (const float*)d_in[3];
    const float* W1r = (const float*)d_in[4];
    const float* W2l = (const float*)d_in[5];
    const float* b2  = (const float*)d_in[6];
    const float* W2r = (const float*)d_in[7];
    const float* W3l = (const float*)d_in[8];
    const float* b3  = (const float*)d_in[9];
    const float* W3r = (const float*)d_in[10];
    const float* Wl1 = (const float*)d_in[11];
    const float* bl1 = (const float*)d_in[12];
    const float* Wl2 = (const float*)d_in[13];
    const float* bl2 = (const float*)d_in[14];
    const float* Wl3 = (const float*)d_in[15];
    const float* bl3 = (const float*)d_in[16];
    float* out = (float*)d_out;

    const int N = in_sizes[0] / 9;
    const int E = in_sizes[1] / 2;

    char* ws = (char*)d_ws;
    size_t off = 0;
    auto alloc = [&](size_t bytes) -> void* {
        void* p = ws + off;
        off += (bytes + 255) & ~(size_t)255;
        return p;
    };
    __half* h16    = (__half*)alloc((size_t)N * 128 * sizeof(__half));  // 25.6 MB
    __half* agg16  = (__half*)alloc((size_t)N * 128 * sizeof(__half));  // 25.6 MB
    __half* m16    = (__half*)alloc((size_t)N * 64 * sizeof(__half));   // 12.8 MB
    __half* a32    = (__half*)alloc((size_t)N * 32 * sizeof(__half));   // 6.4 MB
    int* rs     = (int*)alloc((size_t)(N + 1) * sizeof(int));
    int* csr    = (int*)alloc((size_t)E * sizeof(int));                  // 6.4 MB
    int* staged = (int*)alloc((size_t)E * sizeof(int));                  // 6.4 MB
    _Float16* wpk1  = (_Float16*)alloc(32 * 128 * sizeof(_Float16));
    _Float16* wpk2l = (_Float16*)alloc(128 * 128 * sizeof(_Float16));
    _Float16* wpk2r = (_Float16*)alloc(128 * 128 * sizeof(_Float16));
    _Float16* wpk3l = (_Float16*)alloc(128 * 128 * sizeof(_Float16));
    _Float16* wpk3r = (_Float16*)alloc(128 * 128 * sizeof(_Float16));
    _Float16* wpkl1 = (_Float16*)alloc(128 * 128 * sizeof(_Float16));
    _Float16* wpkl2 = (_Float16*)alloc(128 * 64 * sizeof(_Float16));
    (void)ws_size; (void)n_in; (void)out_size;

    // bucket params (N=100K, E=1.6M -> shift=7, NB=782, NBLK=98)
    int shift = 7;
    while ((((size_t)N + ((size_t)1 << shift) - 1) >> shift) > MAXNB) ++shift;
    const int NB = (N + (1 << shift) - 1) >> shift;
    const int NBLK = (E + CH - 1) / CH;               // must be <= 128
    int* bh    = (int*)alloc((size_t)NB * NBLK * sizeof(int));
    int* btot  = (int*)alloc((size_t)NB * sizeof(int));
    int* bbase = (int*)alloc((size_t)(NB + 1) * sizeof(int));
    int* bsum  = (int*)alloc(64 * sizeof(int));

    // Weight packing (tiny; independent of CSR build)
    wpack1_k<<<2, 256, 0, stream>>>(W1l, W1r, wpk1);
    wpack_k<<<8, 256, 0, stream>>>(W2l, wpk2l, 128, 128);
    wpack_k<<<8, 256, 0, stream>>>(W2r, wpk2r, 128, 128);
    wpack_k<<<8, 256, 0, stream>>>(W3l, wpk3l, 128, 128);
    wpack_k<<<8, 256, 0, stream>>>(W3r, wpk3r, 128, 128);
    wpack_k<<<8, 256, 0, stream>>>(Wl1, wpkl1, 128, 128);
    wpack_k<<<4, 256, 0, stream>>>(Wl2, wpkl2, 128, 64);

    // CSR build (two-level bucket, no global-atomic scatter)
    bhist_k<<<NBLK, 256, 0, stream>>>(ei, bh, E, shift, NB, NBLK);
    scan_col_k<<<NB, 128, 0, stream>>>(bh, btot, NBLK, NB);
    scan_block_k<<<1, 256, 0, stream>>>(btot, bbase, bsum, NB);
    bscatter_k<<<NBLK, 256, 0, stream>>>(ei, bh, bbase, staged, E, shift, NB, NBLK);
    csrfill_k<<<NB, 256, 0, stream>>>(staged, bbase, rs, csr, N, E, shift, NB);

    const int gemm_grid = (N + 63) / 64;
    const int agg_grid = (N + 15) / 16;

    // SAGE layer 1 (9 -> 128): pack [agg9|x9|0] fp16, then K=32 MFMA GEMM
    agg9pack_k<<<(N + 255) / 256, 256, 0, stream>>>(x, rs, csr, a32, N);
    mfma_lin_k<2, 1, 32><<<gemm_grid, 256, 0, stream>>>(
        a32, nullptr, wpk1, nullptr, b1, h16, N);

    // SAGE layer 2 (128 -> 128): gather h1 -> agg16; h2 = relu(agg@W2l + h1@W2r + b2)
    agg128h4_k<<<agg_grid, 256, 0, stream>>>(h16, rs, csr, agg16, N);
    mfma_lin_k<2, 2, 128><<<gemm_grid, 256, 0, stream>>>(
        agg16, h16, wpk2l, wpk2r, b2, h16, N);

    // SAGE layer 3 (128 -> 128)
    agg128h4_k<<<agg_grid, 256, 0, stream>>>(h16, rs, csr, agg16, N);
    mfma_lin_k<2, 2, 128><<<gemm_grid, 256, 0, stream>>>(
        agg16, h16, wpk3l, wpk3r, b3, h16, N);

    // MLP: 128 -> 128 (relu), 128 -> 64 (relu), 64 -> 3 + log_softmax
    mfma_lin_k<2, 1, 128><<<gemm_grid, 256, 0, stream>>>(
        h16, nullptr, wpkl1, nullptr, bl1, h16, N);
    mfma_lin_k<1, 1, 128><<<gemm_grid, 256, 0, stream>>>(
        h16, nullptr, wpkl2, nullptr, bl2, m16, N);
    final_k<<<(N + 255) / 256, 256, 0, stream>>>(m16, Wl3, bl3, out, N);
}

// Round 10
// 312.329 us; speedup vs baseline: 2.5198x; 1.0252x over previous
//
#include <hip/hip_runtime.h>
#include <hip/hip_fp16.h>
#include <stdint.h>

typedef _Float16 f16x8 __attribute__((ext_vector_type(8)));
typedef float f32x4 __attribute__((ext_vector_type(4)));

// ---------------------------------------------------------------- CSR build
// edge_index arrives as int32 (harness converts integer inputs to int32).
// R4: deterministic two-level bucket CSR build (no global-atomic scatter).

#define CH 16384          // edges per block in bucket passes
#define MAXNB 1024        // max bucket count supported by LDS arrays

__global__ __launch_bounds__(256) void bhist_k(const int* __restrict__ ei,
        int* __restrict__ bh, int E, int shift, int NB, int NBLK) {
    __shared__ int lh[MAXNB];
    for (int b = threadIdx.x; b < NB; b += 256) lh[b] = 0;
    __syncthreads();
    int base = blockIdx.x * CH;
    int end = min(base + CH, E);
    for (int e = base + threadIdx.x; e < end; e += 256) {
        int t = ei[(size_t)E + e];
        atomicAdd(&lh[t >> shift], 1);
    }
    __syncthreads();
    for (int b = threadIdx.x; b < NB; b += 256)
        bh[(size_t)b * NBLK + blockIdx.x] = lh[b];   // column-major per bucket
}

__global__ void scan_col_k(int* bh, int* __restrict__ btot, int NBLK, int NB) {
    __shared__ int sd[128];
    int b = blockIdx.x;
    int t = threadIdx.x;
    int v = (t < NBLK) ? bh[(size_t)b * NBLK + t] : 0;
    sd[t] = v;
    __syncthreads();
    for (int off = 1; off < 128; off <<= 1) {
        int x = (t >= off) ? sd[t - off] : 0;
        __syncthreads();
        sd[t] += x;
        __syncthreads();
    }
    if (t < NBLK) bh[(size_t)b * NBLK + t] = sd[t] - v;   // exclusive
    if (t == 127) btot[b] = sd[127];
}

__global__ void scan_block_k(const int* __restrict__ deg, int* __restrict__ excl,
                             int* __restrict__ bsum, int N) {
    __shared__ int sd[256];
    int t = threadIdx.x;
    int base = blockIdx.x * 1024 + t * 4;
    int v0 = (base + 0 < N) ? deg[base + 0] : 0;
    int v1 = (base + 1 < N) ? deg[base + 1] : 0;
    int v2 = (base + 2 < N) ? deg[base + 2] : 0;
    int v3 = (base + 3 < N) ? deg[base + 3] : 0;
    int s = v0 + v1 + v2 + v3;
    sd[t] = s;
    __syncthreads();
    for (int off = 1; off < 256; off <<= 1) {
        int x = (t >= off) ? sd[t - off] : 0;
        __syncthreads();
        sd[t] += x;
        __syncthreads();
    }
    int incl = sd[t];
    int ex = incl - s;
    if (base + 0 < N) excl[base + 0] = ex;
    if (base + 1 < N) excl[base + 1] = ex + v0;
    if (base + 2 < N) excl[base + 2] = ex + v0 + v1;
    if (base + 3 < N) excl[base + 3] = ex + v0 + v1 + v2;
    if (t == 255) bsum[blockIdx.x] = incl;
}

__global__ __launch_bounds__(256) void bscatter_k(const int* __restrict__ ei,
        const int* __restrict__ bh, const int* __restrict__ bbase,
        int* __restrict__ staged, int E, int shift, int NB, int NBLK) {
    __shared__ int cur[MAXNB];
    for (int b = threadIdx.x; b < NB; b += 256)
        cur[b] = bbase[b] + bh[(size_t)b * NBLK + blockIdx.x];
    __syncthreads();
    int base = blockIdx.x * CH;
    int end = min(base + CH, E);
    int mask = (1 << shift) - 1;
    for (int e = base + threadIdx.x; e < end; e += 256) {
        int s = ei[e];
        int t = ei[(size_t)E + e];
        int p = atomicAdd(&cur[t >> shift], 1);
        staged[p] = s | ((t & mask) << 17);
    }
}

__global__ __launch_bounds__(256) void csrfill_k(const int* __restrict__ staged,
        const int* __restrict__ bbase, int* __restrict__ rs, int* __restrict__ csr,
        int N, int E, int shift, int NB) {
    __shared__ int lh[256];
    __shared__ int sd[256];
    int b = blockIdx.x;
    int tpb = 1 << shift;                 // targets per bucket (<=256)
    int t0 = b << shift;
    int s0 = bbase[b];
    int s1 = (b == NB - 1) ? E : bbase[b + 1];
    int t = threadIdx.x;
    if (t < tpb) lh[t] = 0;
    __syncthreads();
    for (int e = s0 + t; e < s1; e += 256)
        atomicAdd(&lh[staged[e] >> 17], 1);
    __syncthreads();
    int v = (t < tpb) ? lh[t] : 0;
    sd[t] = v;
    __syncthreads();
    for (int off = 1; off < 256; off <<= 1) {
        int x = (t >= off) ? sd[t - off] : 0;
        __syncthreads();
        sd[t] += x;
        __syncthreads();
    }
    if (t < tpb) {
        int excl = sd[t] - v;
        lh[t] = excl;                      // reuse as local cursor
        int tg = t0 + t;
        if (tg < N) rs[tg] = s0 + excl;
    }
    if (b == NB - 1 && t == 0) rs[N] = E;
    __syncthreads();
    for (int e = s0 + t; e < s1; e += 256) {
        int w = staged[e];
        int lt = w >> 17;
        int src = w & 0x1FFFF;
        int p = s0 + atomicAdd(&lh[lt], 1);
        csr[p] = src;
    }
}

// ------------------------------------------------------------- aggregation

// Layer-1 aggregation + pack, F=9: one thread per node.
// Emits the padded fp16 A-row [agg9 | x9 | 0...0] for the K=32 MFMA GEMM.
__global__ void agg9pack_k(const float* __restrict__ x, const int* __restrict__ rs,
                           const int* __restrict__ csr, __half* __restrict__ a32,
                           int N) {
    int i = blockIdx.x * blockDim.x + threadIdx.x;
    if (i >= N) return;
    int s0 = rs[i], s1 = rs[i + 1];
    float a[9];
    #pragma unroll
    for (int f = 0; f < 9; ++f) a[f] = 0.f;
    for (int j = s0; j < s1; ++j) {
        const float* p = x + (size_t)csr[j] * 9;
        #pragma unroll
        for (int f = 0; f < 9; ++f) a[f] += p[f];
    }
    float inv = (s1 > s0) ? 1.f / (float)(s1 - s0) : 0.f;
    const float* xr = x + (size_t)i * 9;
    union { _Float16 h[32]; uint4 u4[4]; } o;
    #pragma unroll
    for (int f = 0; f < 9; ++f) o.h[f] = (_Float16)(a[f] * inv);
    #pragma unroll
    for (int f = 0; f < 9; ++f) o.h[9 + f] = (_Float16)xr[f];
    #pragma unroll
    for (int f = 18; f < 32; ++f) o.h[f] = (_Float16)0.f;
    uint4* dst = reinterpret_cast<uint4*>(a32 + (size_t)i * 32);
    #pragma unroll
    for (int q = 0; q < 4; ++q) dst[q] = o.u4[q];
}

// F=128 fp16 aggregation: 4 nodes per wave, 16 lanes per row, uint4 (16B)/lane.
// R10: R8 kept in-flight bytes/wave at 4KB (4x1KB vs R7's 8x512B) -> same
// latency-BW product, only 1.23x gain. Kernel is outstanding-bytes bound
// (beyond-L2 path at 3.1 TB/s, far under ceiling). 8-deep unroll doubles
// in-flight to 8KB/wave. VGPR ~60, still 8 waves/SIMD (halves above 64).
__global__ __launch_bounds__(256) void agg128h4_k(const __half* __restrict__ h16,
        const int* __restrict__ rs, const int* __restrict__ csr,
        __half* __restrict__ out, int N) {
    int l16 = threadIdx.x & 15;
    int node = blockIdx.x * 16 + (threadIdx.x >> 4);
    if (node >= N) return;
    int s0 = rs[node], s1 = rs[node + 1];
    const uint4* h4 = reinterpret_cast<const uint4*>(h16);   // N x 16 uint4
    float acc[8];
    #pragma unroll
    for (int c = 0; c < 8; ++c) acc[c] = 0.f;
    int j = s0;
    for (; j + 8 <= s1; j += 8) {
        int n[8];
        #pragma unroll
        for (int u = 0; u < 8; ++u) n[u] = csr[j + u];
        uint4 v[8];
        #pragma unroll
        for (int u = 0; u < 8; ++u)
            v[u] = h4[(size_t)n[u] * 16 + l16];
        #pragma unroll
        for (int u = 0; u < 8; ++u) {
            const __half2* p = reinterpret_cast<const __half2*>(&v[u]);
            #pragma unroll
            for (int q = 0; q < 4; ++q) {
                float2 f = __half22float2(p[q]);
                acc[q * 2]     += f.x;
                acc[q * 2 + 1] += f.y;
            }
        }
    }
    for (; j + 4 <= s1; j += 4) {
        uint4 v[4];
        #pragma unroll
        for (int u = 0; u < 4; ++u)
            v[u] = h4[(size_t)csr[j + u] * 16 + l16];
        #pragma unroll
        for (int u = 0; u < 4; ++u) {
            const __half2* p = reinterpret_cast<const __half2*>(&v[u]);
            #pragma unroll
            for (int q = 0; q < 4; ++q) {
                float2 f = __half22float2(p[q]);
                acc[q * 2]     += f.x;
                acc[q * 2 + 1] += f.y;
            }
        }
    }
    for (; j < s1; ++j) {
        uint4 vv = h4[(size_t)csr[j] * 16 + l16];
        const __half2* p = reinterpret_cast<const __half2*>(&vv);
        #pragma unroll
        for (int q = 0; q < 4; ++q) {
            float2 f = __half22float2(p[q]);
            acc[q * 2]     += f.x;
            acc[q * 2 + 1] += f.y;
        }
    }
    float inv = (s1 > s0) ? 1.f / (float)(s1 - s0) : 0.f;
    __half2 o[4];
    #pragma unroll
    for (int q = 0; q < 4; ++q)
        o[q] = __floats2half2_rn(acc[q * 2] * inv, acc[q * 2 + 1] * inv);
    reinterpret_cast<uint4*>(out)[(size_t)node * 16 + l16] =
        *reinterpret_cast<uint4*>(o);
}

// ------------------------------------------------------------------- GEMMs

// Pack fp32 W[K][N] into MFMA B-fragment order, fp16 (m89/m92 layout).
// R10: all six 128/64-wide weights in ONE launch (descriptor table by-value).
struct WPD { const float* W; _Float16* dst; int K, N; };
struct WPD6 { WPD d[6]; };

__global__ void wpack6_k(WPD6 all) {
    WPD w = all.d[blockIdx.y];
    int idx = blockIdx.x * blockDim.x + threadIdx.x;
    int kcb = w.K / 32;
    int total = (w.N / 16) * kcb * 64;
    if (idx >= total) return;
    int lane = idx & 63;
    int blk = idx >> 6;
    int kb = blk % kcb;
    int nf = blk / kcb;
    int col = nf * 16 + (lane & 15);
    int k0 = kb * 32 + (lane >> 4) * 8;
    f16x8 v;
    #pragma unroll
    for (int j = 0; j < 8; ++j)
        v[j] = (_Float16)w.W[(size_t)(k0 + j) * w.N + col];
    *reinterpret_cast<f16x8*>(w.dst + (size_t)idx * 8) = v;
}

// Pack layer-1 combined weight [W1l(9x128); W1r(9x128); 0...] as K=32, N=128.
__global__ void wpack1_k(const float* __restrict__ Wl, const float* __restrict__ Wr,
                         _Float16* __restrict__ wpk) {
    int idx = blockIdx.x * blockDim.x + threadIdx.x;
    if (idx >= 8 * 64) return;               // (N/16=8) * (KB=1) * 64
    int lane = idx & 63;
    int nf = idx >> 6;
    int col = nf * 16 + (lane & 15);
    int k0 = (lane >> 4) * 8;
    f16x8 v;
    #pragma unroll
    for (int j = 0; j < 8; ++j) {
        int k = k0 + j;
        float w = (k < 9) ? Wl[(size_t)k * 128 + col]
                : (k < 18) ? Wr[(size_t)(k - 9) * 128 + col] : 0.f;
        v[j] = (_Float16)w;
    }
    *reinterpret_cast<f16x8*>(wpk + (size_t)idx * 8) = v;
}

// MFMA fp16 GEMM: C[M,TN] = relu(A1@W1 (+ A2@W2) + bias), fp32 accum, fp16 out.
// Block: 64 rows x TN cols, 4 waves; wave owns NF 16-col frags; K = KK.
// Row-wise in-place (C == A1 or A2) is safe.
template<int NF, int NS, int KK>
__global__ __launch_bounds__(256) void mfma_lin_k(
        const __half* A1, const __half* A2,
        const _Float16* __restrict__ pk1, const _Float16* __restrict__ pk2,
        const float* __restrict__ bias, __half* C, int M) {
    constexpr int TN = 64 * NF;          // 128 or 64
    constexpr int KB = KK / 32;
    constexpr int LPR = KK / 8;          // uint4 loads per row
    constexpr int RPI = 256 / LPR;       // rows staged per iteration
    constexpr int ITER = 64 / RPI;
    __shared__ _Float16 a_lds[NS][64][KK + 8];

    int tid = threadIdx.x;
    int lane = tid & 63;
    int wave = tid >> 6;
    int rb = blockIdx.x * 64;

    const __half* As[2] = {A1, A2};
    #pragma unroll
    for (int s = 0; s < NS; ++s) {
        #pragma unroll
        for (int i = 0; i < ITER; ++i) {
            int row = (tid / LPR) + i * RPI;
            int c = tid % LPR;
            int grow = rb + row;
            uint4 v = make_uint4(0, 0, 0, 0);
            if (grow < M)
                v = reinterpret_cast<const uint4*>(As[s] + (size_t)grow * KK)[c];
            *reinterpret_cast<uint4*>(&a_lds[s][row][c * 8]) = v;
        }
    }

    const _Float16* pks[2] = {pk1, pk2};
    f16x8 bfrag[NS][KB][NF];
    #pragma unroll
    for (int s = 0; s < NS; ++s)
        #pragma unroll
        for (int kb = 0; kb < KB; ++kb)
            #pragma unroll
            for (int n = 0; n < NF; ++n) {
                int nf = wave * NF + n;
                bfrag[s][kb][n] =
                    reinterpret_cast<const f16x8*>(pks[s])[(size_t)(nf * KB + kb) * 64 + lane];
            }

    f32x4 acc[4][NF];
    #pragma unroll
    for (int m = 0; m < 4; ++m)
        #pragma unroll
        for (int n = 0; n < NF; ++n)
            acc[m][n] = (f32x4){0.f, 0.f, 0.f, 0.f};

    __syncthreads();

    #pragma unroll
    for (int s = 0; s < NS; ++s)
        #pragma unroll
        for (int kb = 0; kb < KB; ++kb)
            #pragma unroll
            for (int m = 0; m < 4; ++m) {
                f16x8 a = *reinterpret_cast<const f16x8*>(
                    &a_lds[s][m * 16 + (lane & 15)][kb * 32 + (lane >> 4) * 8]);
                #pragma unroll
                for (int n = 0; n < NF; ++n)
                    acc[m][n] = __builtin_amdgcn_mfma_f32_16x16x32_f16(
                        a, bfrag[s][kb][n], acc[m][n], 0, 0, 0);
            }

    #pragma unroll
    for (int n = 0; n < NF; ++n) {
        int col = wave * NF * 16 + n * 16 + (lane & 15);
        float bv = bias[col];
        #pragma unroll
        for (int m = 0; m < 4; ++m) {
            #pragma unroll
            for (int j = 0; j < 4; ++j) {
                int grow = rb + m * 16 + (lane >> 4) * 4 + j;
                if (grow < M) {
                    float v = fmaxf(acc[m][n][j] + bv, 0.f);
                    C[(size_t)grow * TN + col] = __float2half_rn(v);
                }
            }
        }
    }
}

// Final: [N,64] fp16 @ [64,3] fp32 + b, then log_softmax. One thread per node.
__global__ void final_k(const __half* __restrict__ m2, const float* __restrict__ W,
                        const float* __restrict__ b, float* __restrict__ out, int N) {
    int i = blockIdx.x * blockDim.x + threadIdx.x;
    if (i >= N) return;
    const f16x8* r8 = reinterpret_cast<const f16x8*>(m2 + (size_t)i * 64);
    float l0 = b[0], l1 = b[1], l2 = b[2];
    #pragma unroll
    for (int q = 0; q < 8; ++q) {
        f16x8 v8 = r8[q];
        #pragma unroll
        for (int j = 0; j < 8; ++j) {
            float v = (float)v8[j];
            int k = q * 8 + j;
            l0 = fmaf(v, W[k * 3 + 0], l0);
            l1 = fmaf(v, W[k * 3 + 1], l1);
            l2 = fmaf(v, W[k * 3 + 2], l2);
        }
    }
    float mx = fmaxf(l0, fmaxf(l1, l2));
    float e0 = expf(l0 - mx), e1 = expf(l1 - mx), e2 = expf(l2 - mx);
    float lse = logf(e0 + e1 + e2) + mx;
    out[(size_t)i * 3 + 0] = l0 - lse;
    out[(size_t)i * 3 + 1] = l1 - lse;
    out[(size_t)i * 3 + 2] = l2 - lse;
}

// ------------------------------------------------------------------ launch

extern "C" void kernel_launch(void* const* d_in, const int* in_sizes, int n_in,
                              void* d_out, int out_size, void* d_ws, size_t ws_size,
                              hipStream_t stream) {
    const float* x   = (const float*)d_in[0];
    const int* ei    = (const int*)d_in[1];   // int32 (harness-converted)
    const float* W1l = (const float*)d_in[2];
    const float* b1  = (const float*)d_in[3];
    const float* W1r = (const float*)d_in[4];
    const float* W2l = (const float*)d_in[5];
    const float* b2  = (const float*)d_in[6];
    const float* W2r = (const float*)d_in[7];
    const float* W3l = (const float*)d_in[8];
    const float* b3  = (const float*)d_in[9];
    const float* W3r = (const float*)d_in[10];
    const float* Wl1 = (const float*)d_in[11];
    const float* bl1 = (const float*)d_in[12];
    const float* Wl2 = (const float*)d_in[13];
    const float* bl2 = (const float*)d_in[14];
    const float* Wl3 = (const float*)d_in[15];
    const float* bl3 = (const float*)d_in[16];
    float* out = (float*)d_out;

    const int N = in_sizes[0] / 9;
    const int E = in_sizes[1] / 2;

    char* ws = (char*)d_ws;
    size_t off = 0;
    auto alloc = [&](size_t bytes) -> void* {
        void* p = ws + off;
        off += (bytes + 255) & ~(size_t)255;
        return p;
    };
    __half* h16    = (__half*)alloc((size_t)N * 128 * sizeof(__half));  // 25.6 MB
    __half* agg16  = (__half*)alloc((size_t)N * 128 * sizeof(__half));  // 25.6 MB
    __half* m16    = (__half*)alloc((size_t)N * 64 * sizeof(__half));   // 12.8 MB
    __half* a32    = (__half*)alloc((size_t)N * 32 * sizeof(__half));   // 6.4 MB
    int* rs     = (int*)alloc((size_t)(N + 1) * sizeof(int));
    int* csr    = (int*)alloc((size_t)E * sizeof(int));                  // 6.4 MB
    int* staged = (int*)alloc((size_t)E * sizeof(int));                  // 6.4 MB
    _Float16* wpk1  = (_Float16*)alloc(32 * 128 * sizeof(_Float16));
    _Float16* wpk2l = (_Float16*)alloc(128 * 128 * sizeof(_Float16));
    _Float16* wpk2r = (_Float16*)alloc(128 * 128 * sizeof(_Float16));
    _Float16* wpk3l = (_Float16*)alloc(128 * 128 * sizeof(_Float16));
    _Float16* wpk3r = (_Float16*)alloc(128 * 128 * sizeof(_Float16));
    _Float16* wpkl1 = (_Float16*)alloc(128 * 128 * sizeof(_Float16));
    _Float16* wpkl2 = (_Float16*)alloc(128 * 64 * sizeof(_Float16));
    (void)ws_size; (void)n_in; (void)out_size;

    // bucket params (N=100K, E=1.6M -> shift=7, NB=782, NBLK=98)
    int shift = 7;
    while ((((size_t)N + ((size_t)1 << shift) - 1) >> shift) > MAXNB) ++shift;
    const int NB = (N + (1 << shift) - 1) >> shift;
    const int NBLK = (E + CH - 1) / CH;               // must be <= 128
    int* bh    = (int*)alloc((size_t)NB * NBLK * sizeof(int));
    int* btot  = (int*)alloc((size_t)NB * sizeof(int));
    int* bbase = (int*)alloc((size_t)(NB + 1) * sizeof(int));
    int* bsum  = (int*)alloc(64 * sizeof(int));

    // Weight packing: one launch for the six K>=64 weights + layer-1 special
    WPD6 wp;
    wp.d[0] = {W2l, wpk2l, 128, 128};
    wp.d[1] = {W2r, wpk2r, 128, 128};
    wp.d[2] = {W3l, wpk3l, 128, 128};
    wp.d[3] = {W3r, wpk3r, 128, 128};
    wp.d[4] = {Wl1, wpkl1, 128, 128};
    wp.d[5] = {Wl2, wpkl2, 128, 64};
    wpack6_k<<<dim3(8, 6), 256, 0, stream>>>(wp);
    wpack1_k<<<2, 256, 0, stream>>>(W1l, W1r, wpk1);

    // CSR build (two-level bucket, no global-atomic scatter)
    bhist_k<<<NBLK, 256, 0, stream>>>(ei, bh, E, shift, NB, NBLK);
    scan_col_k<<<NB, 128, 0, stream>>>(bh, btot, NBLK, NB);
    scan_block_k<<<1, 256, 0, stream>>>(btot, bbase, bsum, NB);
    bscatter_k<<<NBLK, 256, 0, stream>>>(ei, bh, bbase, staged, E, shift, NB, NBLK);
    csrfill_k<<<NB, 256, 0, stream>>>(staged, bbase, rs, csr, N, E, shift, NB);

    const int gemm_grid = (N + 63) / 64;
    const int agg_grid = (N + 15) / 16;

    // SAGE layer 1 (9 -> 128): pack [agg9|x9|0] fp16, then K=32 MFMA GEMM
    agg9pack_k<<<(N + 255) / 256, 256, 0, stream>>>(x, rs, csr, a32, N);
    mfma_lin_k<2, 1, 32><<<gemm_grid, 256, 0, stream>>>(
        a32, nullptr, wpk1, nullptr, b1, h16, N);

    // SAGE layer 2 (128 -> 128): gather h1 -> agg16; h2 = relu(agg@W2l + h1@W2r + b2)
    agg128h4_k<<<agg_grid, 256, 0, stream>>>(h16, rs, csr, agg16, N);
    mfma_lin_k<2, 2, 128><<<gemm_grid, 256, 0, stream>>>(
        agg16, h16, wpk2l, wpk2r, b2, h16, N);

    // SAGE layer 3 (128 -> 128)
    agg128h4_k<<<agg_grid, 256, 0, stream>>>(h16, rs, csr, agg16, N);
    mfma_lin_k<2, 2, 128><<<gemm_grid, 256, 0, stream>>>(
        agg16, h16, wpk3l, wpk3r, b3, h16, N);

    // MLP: 128 -> 128 (relu), 128 -> 64 (relu), 64 -> 3 + log_softmax
    mfma_lin_k<2, 1, 128><<<gemm_grid, 256, 0, stream>>>(
        h16, nullptr, wpkl1, nullptr, bl1, h16, N);
    mfma_lin_k<1, 1, 128><<<gemm_grid, 256, 0, stream>>>(
        h16, nullptr, wpkl2, nullptr, bl2, m16, N);
    final_k<<<(N + 255) / 256, 256, 0, stream>>>(m16, Wl3, bl3, out, N);
}

// Round 11
// 294.765 us; speedup vs baseline: 2.6700x; 1.0596x over previous
//
#include <hip/hip_runtime.h>
#include <hip/hip_fp16.h>
#include <stdint.h>

typedef _Float16 f16x8 __attribute__((ext_vector_type(8)));
typedef float f32x4 __attribute__((ext_vector_type(4)));

// ---------------------------------------------------------------- CSR build
// edge_index arrives as int32 (harness converts integer inputs to int32).
// R4: deterministic two-level bucket CSR build (no global-atomic scatter).
// R11: CH 16384->2048 (98->782 blocks; bhist/bscatter were at 38% CU
// coverage); scan_col generalized to 1024-capacity (256 thr x 4).

#define CH 2048           // edges per block in bucket passes
#define MAXNB 1024        // max bucket count supported by LDS arrays
#define MAXNBLK 1024      // max block count in bucket passes (scan capacity)

__global__ __launch_bounds__(256) void bhist_k(const int* __restrict__ ei,
        int* __restrict__ bh, int E, int shift, int NB, int NBLK) {
    __shared__ int lh[MAXNB];
    for (int b = threadIdx.x; b < NB; b += 256) lh[b] = 0;
    __syncthreads();
    int base = blockIdx.x * CH;
    int end = min(base + CH, E);
    for (int e = base + threadIdx.x; e < end; e += 256) {
        int t = ei[(size_t)E + e];
        atomicAdd(&lh[t >> shift], 1);
    }
    __syncthreads();
    for (int b = threadIdx.x; b < NB; b += 256)
        bh[(size_t)b * NBLK + blockIdx.x] = lh[b];   // column-major per bucket
}

// Exclusive scan of each bucket's per-block counts (NBLK <= 1024).
__global__ __launch_bounds__(256) void scan_col_k(int* bh, int* __restrict__ btot,
                                                  int NBLK, int NB) {
    __shared__ int sd[256];
    size_t rowoff = (size_t)blockIdx.x * NBLK;
    int t = threadIdx.x;
    int base = t * 4;
    int v0 = (base + 0 < NBLK) ? bh[rowoff + base + 0] : 0;
    int v1 = (base + 1 < NBLK) ? bh[rowoff + base + 1] : 0;
    int v2 = (base + 2 < NBLK) ? bh[rowoff + base + 2] : 0;
    int v3 = (base + 3 < NBLK) ? bh[rowoff + base + 3] : 0;
    int s = v0 + v1 + v2 + v3;
    sd[t] = s;
    __syncthreads();
    for (int off = 1; off < 256; off <<= 1) {
        int x = (t >= off) ? sd[t - off] : 0;
        __syncthreads();
        sd[t] += x;
        __syncthreads();
    }
    int ex = sd[t] - s;
    if (base + 0 < NBLK) bh[rowoff + base + 0] = ex;
    if (base + 1 < NBLK) bh[rowoff + base + 1] = ex + v0;
    if (base + 2 < NBLK) bh[rowoff + base + 2] = ex + v0 + v1;
    if (base + 3 < NBLK) bh[rowoff + base + 3] = ex + v0 + v1 + v2;
    if (t == 255) btot[blockIdx.x] = sd[255];
}

__global__ void scan_block_k(const int* __restrict__ deg, int* __restrict__ excl,
                             int* __restrict__ bsum, int N) {
    __shared__ int sd[256];
    int t = threadIdx.x;
    int base = blockIdx.x * 1024 + t * 4;
    int v0 = (base + 0 < N) ? deg[base + 0] : 0;
    int v1 = (base + 1 < N) ? deg[base + 1] : 0;
    int v2 = (base + 2 < N) ? deg[base + 2] : 0;
    int v3 = (base + 3 < N) ? deg[base + 3] : 0;
    int s = v0 + v1 + v2 + v3;
    sd[t] = s;
    __syncthreads();
    for (int off = 1; off < 256; off <<= 1) {
        int x = (t >= off) ? sd[t - off] : 0;
        __syncthreads();
        sd[t] += x;
        __syncthreads();
    }
    int incl = sd[t];
    int ex = incl - s;
    if (base + 0 < N) excl[base + 0] = ex;
    if (base + 1 < N) excl[base + 1] = ex + v0;
    if (base + 2 < N) excl[base + 2] = ex + v0 + v1;
    if (base + 3 < N) excl[base + 3] = ex + v0 + v1 + v2;
    if (t == 255) bsum[blockIdx.x] = incl;
}

__global__ __launch_bounds__(256) void bscatter_k(const int* __restrict__ ei,
        const int* __restrict__ bh, const int* __restrict__ bbase,
        int* __restrict__ staged, int E, int shift, int NB, int NBLK) {
    __shared__ int cur[MAXNB];
    for (int b = threadIdx.x; b < NB; b += 256)
        cur[b] = bbase[b] + bh[(size_t)b * NBLK + blockIdx.x];
    __syncthreads();
    int base = blockIdx.x * CH;
    int end = min(base + CH, E);
    int mask = (1 << shift) - 1;
    for (int e = base + threadIdx.x; e < end; e += 256) {
        int s = ei[e];
        int t = ei[(size_t)E + e];
        int p = atomicAdd(&cur[t >> shift], 1);
        staged[p] = s | ((t & mask) << 17);
    }
}

__global__ __launch_bounds__(256) void csrfill_k(const int* __restrict__ staged,
        const int* __restrict__ bbase, int* __restrict__ rs, int* __restrict__ csr,
        int N, int E, int shift, int NB) {
    __shared__ int lh[256];
    __shared__ int sd[256];
    int b = blockIdx.x;
    int tpb = 1 << shift;                 // targets per bucket (<=256)
    int t0 = b << shift;
    int s0 = bbase[b];
    int s1 = (b == NB - 1) ? E : bbase[b + 1];
    int t = threadIdx.x;
    if (t < tpb) lh[t] = 0;
    __syncthreads();
    for (int e = s0 + t; e < s1; e += 256)
        atomicAdd(&lh[staged[e] >> 17], 1);
    __syncthreads();
    int v = (t < tpb) ? lh[t] : 0;
    sd[t] = v;
    __syncthreads();
    for (int off = 1; off < 256; off <<= 1) {
        int x = (t >= off) ? sd[t - off] : 0;
        __syncthreads();
        sd[t] += x;
        __syncthreads();
    }
    if (t < tpb) {
        int excl = sd[t] - v;
        lh[t] = excl;                      // reuse as local cursor
        int tg = t0 + t;
        if (tg < N) rs[tg] = s0 + excl;
    }
    if (b == NB - 1 && t == 0) rs[N] = E;
    __syncthreads();
    for (int e = s0 + t; e < s1; e += 256) {
        int w = staged[e];
        int lt = w >> 17;
        int src = w & 0x1FFFF;
        int p = s0 + atomicAdd(&lh[lt], 1);
        csr[p] = src;
    }
}

// ------------------------------------------------------------- aggregation

// Layer-1 aggregation + pack, F=9: one thread per node.
// Emits the padded fp16 A-row [agg9 | x9 | 0...0] for the K=32 MFMA GEMM.
__global__ void agg9pack_k(const float* __restrict__ x, const int* __restrict__ rs,
                           const int* __restrict__ csr, __half* __restrict__ a32,
                           int N) {
    int i = blockIdx.x * blockDim.x + threadIdx.x;
    if (i >= N) return;
    int s0 = rs[i], s1 = rs[i + 1];
    float a[9];
    #pragma unroll
    for (int f = 0; f < 9; ++f) a[f] = 0.f;
    for (int j = s0; j < s1; ++j) {
        const float* p = x + (size_t)csr[j] * 9;
        #pragma unroll
        for (int f = 0; f < 9; ++f) a[f] += p[f];
    }
    float inv = (s1 > s0) ? 1.f / (float)(s1 - s0) : 0.f;
    const float* xr = x + (size_t)i * 9;
    union { _Float16 h[32]; uint4 u4[4]; } o;
    #pragma unroll
    for (int f = 0; f < 9; ++f) o.h[f] = (_Float16)(a[f] * inv);
    #pragma unroll
    for (int f = 0; f < 9; ++f) o.h[9 + f] = (_Float16)xr[f];
    #pragma unroll
    for (int f = 18; f < 32; ++f) o.h[f] = (_Float16)0.f;
    uint4* dst = reinterpret_cast<uint4*>(a32 + (size_t)i * 32);
    #pragma unroll
    for (int q = 0; q < 4; ++q) dst[q] = o.u4[q];
}

// F=128 fp16 aggregation: 4 nodes per wave, 16 lanes per row, uint4 (16B)/lane.
// R11: reverted to 4-deep unroll (R10's 8-deep: identical 58us, VGPR 28->44,
// occupancy 68->44% — CU-level in-flight bytes invariant under both payload
// (R8) and depth (R10) => random-gather delivery ceiling ~7.1 TB/s. Treat
// 2x58us as the aggregation floor for a random graph at fp16 payload.)
__global__ __launch_bounds__(256) void agg128h4_k(const __half* __restrict__ h16,
        const int* __restrict__ rs, const int* __restrict__ csr,
        __half* __restrict__ out, int N) {
    int l16 = threadIdx.x & 15;
    int node = blockIdx.x * 16 + (threadIdx.x >> 4);
    if (node >= N) return;
    int s0 = rs[node], s1 = rs[node + 1];
    const uint4* h4 = reinterpret_cast<const uint4*>(h16);   // N x 16 uint4
    float acc[8];
    #pragma unroll
    for (int c = 0; c < 8; ++c) acc[c] = 0.f;
    int j = s0;
    for (; j + 4 <= s1; j += 4) {
        uint4 v[4];
        #pragma unroll
        for (int u = 0; u < 4; ++u)
            v[u] = h4[(size_t)csr[j + u] * 16 + l16];
        #pragma unroll
        for (int u = 0; u < 4; ++u) {
            const __half2* p = reinterpret_cast<const __half2*>(&v[u]);
            #pragma unroll
            for (int q = 0; q < 4; ++q) {
                float2 f = __half22float2(p[q]);
                acc[q * 2]     += f.x;
                acc[q * 2 + 1] += f.y;
            }
        }
    }
    for (; j < s1; ++j) {
        uint4 vv = h4[(size_t)csr[j] * 16 + l16];
        const __half2* p = reinterpret_cast<const __half2*>(&vv);
        #pragma unroll
        for (int q = 0; q < 4; ++q) {
            float2 f = __half22float2(p[q]);
            acc[q * 2]     += f.x;
            acc[q * 2 + 1] += f.y;
        }
    }
    float inv = (s1 > s0) ? 1.f / (float)(s1 - s0) : 0.f;
    __half2 o[4];
    #pragma unroll
    for (int q = 0; q < 4; ++q)
        o[q] = __floats2half2_rn(acc[q * 2] * inv, acc[q * 2 + 1] * inv);
    reinterpret_cast<uint4*>(out)[(size_t)node * 16 + l16] =
        *reinterpret_cast<uint4*>(o);
}

// ------------------------------------------------------------------- GEMMs

// Pack fp32 W[K][N] into MFMA B-fragment order, fp16 (m89/m92 layout).
struct WPD { const float* W; _Float16* dst; int K, N; };
struct WPD6 { WPD d[6]; };

__global__ void wpack6_k(WPD6 all) {
    WPD w = all.d[blockIdx.y];
    int idx = blockIdx.x * blockDim.x + threadIdx.x;
    int kcb = w.K / 32;
    int total = (w.N / 16) * kcb * 64;
    if (idx >= total) return;
    int lane = idx & 63;
    int blk = idx >> 6;
    int kb = blk % kcb;
    int nf = blk / kcb;
    int col = nf * 16 + (lane & 15);
    int k0 = kb * 32 + (lane >> 4) * 8;
    f16x8 v;
    #pragma unroll
    for (int j = 0; j < 8; ++j)
        v[j] = (_Float16)w.W[(size_t)(k0 + j) * w.N + col];
    *reinterpret_cast<f16x8*>(w.dst + (size_t)idx * 8) = v;
}

// Pack layer-1 combined weight [W1l(9x128); W1r(9x128); 0...] as K=32, N=128.
__global__ void wpack1_k(const float* __restrict__ Wl, const float* __restrict__ Wr,
                         _Float16* __restrict__ wpk) {
    int idx = blockIdx.x * blockDim.x + threadIdx.x;
    if (idx >= 8 * 64) return;               // (N/16=8) * (KB=1) * 64
    int lane = idx & 63;
    int nf = idx >> 6;
    int col = nf * 16 + (lane & 15);
    int k0 = (lane >> 4) * 8;
    f16x8 v;
    #pragma unroll
    for (int j = 0; j < 8; ++j) {
        int k = k0 + j;
        float w = (k < 9) ? Wl[(size_t)k * 128 + col]
                : (k < 18) ? Wr[(size_t)(k - 9) * 128 + col] : 0.f;
        v[j] = (_Float16)w;
    }
    *reinterpret_cast<f16x8*>(wpk + (size_t)idx * 8) = v;
}

// MFMA fp16 GEMM: C[M,TN] = relu(A1@W1 (+ A2@W2) + bias), fp32 accum, fp16 out.
// Block: 64 rows x TN cols, 4 waves; wave owns NF 16-col frags; K = KK.
// Row-wise in-place (C == A1 or A2) is safe.
template<int NF, int NS, int KK>
__global__ __launch_bounds__(256) void mfma_lin_k(
        const __half* A1, const __half* A2,
        const _Float16* __restrict__ pk1, const _Float16* __restrict__ pk2,
        const float* __restrict__ bias, __half* C, int M) {
    constexpr int TN = 64 * NF;          // 128 or 64
    constexpr int KB = KK / 32;
    constexpr int LPR = KK / 8;          // uint4 loads per row
    constexpr int RPI = 256 / LPR;       // rows staged per iteration
    constexpr int ITER = 64 / RPI;
    __shared__ _Float16 a_lds[NS][64][KK + 8];

    int tid = threadIdx.x;
    int lane = tid & 63;
    int wave = tid >> 6;
    int rb = blockIdx.x * 64;

    const __half* As[2] = {A1, A2};
    #pragma unroll
    for (int s = 0; s < NS; ++s) {
        #pragma unroll
        for (int i = 0; i < ITER; ++i) {
            int row = (tid / LPR) + i * RPI;
            int c = tid % LPR;
            int grow = rb + row;
            uint4 v = make_uint4(0, 0, 0, 0);
            if (grow < M)
                v = reinterpret_cast<const uint4*>(As[s] + (size_t)grow * KK)[c];
            *reinterpret_cast<uint4*>(&a_lds[s][row][c * 8]) = v;
        }
    }

    const _Float16* pks[2] = {pk1, pk2};
    f16x8 bfrag[NS][KB][NF];
    #pragma unroll
    for (int s = 0; s < NS; ++s)
        #pragma unroll
        for (int kb = 0; kb < KB; ++kb)
            #pragma unroll
            for (int n = 0; n < NF; ++n) {
                int nf = wave * NF + n;
                bfrag[s][kb][n] =
                    reinterpret_cast<const f16x8*>(pks[s])[(size_t)(nf * KB + kb) * 64 + lane];
            }

    f32x4 acc[4][NF];
    #pragma unroll
    for (int m = 0; m < 4; ++m)
        #pragma unroll
        for (int n = 0; n < NF; ++n)
            acc[m][n] = (f32x4){0.f, 0.f, 0.f, 0.f};

    __syncthreads();

    #pragma unroll
    for (int s = 0; s < NS; ++s)
        #pragma unroll
        for (int kb = 0; kb < KB; ++kb)
            #pragma unroll
            for (int m = 0; m < 4; ++m) {
                f16x8 a = *reinterpret_cast<const f16x8*>(
                    &a_lds[s][m * 16 + (lane & 15)][kb * 32 + (lane >> 4) * 8]);
                #pragma unroll
                for (int n = 0; n < NF; ++n)
                    acc[m][n] = __builtin_amdgcn_mfma_f32_16x16x32_f16(
                        a, bfrag[s][kb][n], acc[m][n], 0, 0, 0);
            }

    #pragma unroll
    for (int n = 0; n < NF; ++n) {
        int col = wave * NF * 16 + n * 16 + (lane & 15);
        float bv = bias[col];
        #pragma unroll
        for (int m = 0; m < 4; ++m) {
            #pragma unroll
            for (int j = 0; j < 4; ++j) {
                int grow = rb + m * 16 + (lane >> 4) * 4 + j;
                if (grow < M) {
                    float v = fmaxf(acc[m][n][j] + bv, 0.f);
                    C[(size_t)grow * TN + col] = __float2half_rn(v);
                }
            }
        }
    }
}

// R11: fused tail — MLP2 (128->64, relu) + final 64->3 matvec + log_softmax.
// GEMM part identical to mfma_lin_k<1,1,128>; epilogue stages the 64x64
// activation block in LDS, then 64 threads finish per-row logits + softmax.
// Saves one dispatch + the 25.6 MB m16 round trip.
__global__ __launch_bounds__(256) void mfma_lin_final_k(
        const __half* A1, const _Float16* __restrict__ pk1,
        const float* __restrict__ bias,
        const float* __restrict__ W3, const float* __restrict__ b3,
        float* __restrict__ outp, int M) {
    constexpr int KK = 128;
    __shared__ _Float16 a_lds[64][136];
    __shared__ float smem[64][68];

    int tid = threadIdx.x;
    int lane = tid & 63;
    int wave = tid >> 6;
    int rb = blockIdx.x * 64;

    #pragma unroll
    for (int i = 0; i < 4; ++i) {
        int row = (tid >> 4) + i * 16;
        int grow = rb + row;
        uint4 v = make_uint4(0, 0, 0, 0);
        if (grow < M)
            v = reinterpret_cast<const uint4*>(A1 + (size_t)grow * KK)[tid & 15];
        *reinterpret_cast<uint4*>(&a_lds[row][(tid & 15) * 8]) = v;
    }

    f16x8 bfrag[4];
    #pragma unroll
    for (int kb = 0; kb < 4; ++kb)
        bfrag[kb] = reinterpret_cast<const f16x8*>(pk1)[(size_t)(wave * 4 + kb) * 64 + lane];

    f32x4 acc[4];
    #pragma unroll
    for (int m = 0; m < 4; ++m) acc[m] = (f32x4){0.f, 0.f, 0.f, 0.f};

    __syncthreads();

    #pragma unroll
    for (int kb = 0; kb < 4; ++kb)
        #pragma unroll
        for (int m = 0; m < 4; ++m) {
            f16x8 a = *reinterpret_cast<const f16x8*>(
                &a_lds[m * 16 + (lane & 15)][kb * 32 + (lane >> 4) * 8]);
            acc[m] = __builtin_amdgcn_mfma_f32_16x16x32_f16(a, bfrag[kb], acc[m], 0, 0, 0);
        }

    int col = wave * 16 + (lane & 15);
    float bv = bias[col];
    #pragma unroll
    for (int m = 0; m < 4; ++m)
        #pragma unroll
        for (int j = 0; j < 4; ++j) {
            int row = m * 16 + (lane >> 4) * 4 + j;
            smem[row][col] = fmaxf(acc[m][j] + bv, 0.f);
        }
    __syncthreads();

    if (tid < 64) {
        int grow = rb + tid;
        if (grow < M) {
            float l0 = b3[0], l1 = b3[1], l2 = b3[2];
            #pragma unroll 8
            for (int k = 0; k < 64; ++k) {
                float v = smem[tid][k];
                l0 = fmaf(v, W3[k * 3 + 0], l0);
                l1 = fmaf(v, W3[k * 3 + 1], l1);
                l2 = fmaf(v, W3[k * 3 + 2], l2);
            }
            float mx = fmaxf(l0, fmaxf(l1, l2));
            float e0 = expf(l0 - mx), e1 = expf(l1 - mx), e2 = expf(l2 - mx);
            float lse = logf(e0 + e1 + e2) + mx;
            outp[(size_t)grow * 3 + 0] = l0 - lse;
            outp[(size_t)grow * 3 + 1] = l1 - lse;
            outp[(size_t)grow * 3 + 2] = l2 - lse;
        }
    }
}

// ------------------------------------------------------------------ launch

extern "C" void kernel_launch(void* const* d_in, const int* in_sizes, int n_in,
                              void* d_out, int out_size, void* d_ws, size_t ws_size,
                              hipStream_t stream) {
    const float* x   = (const float*)d_in[0];
    const int* ei    = (const int*)d_in[1];   // int32 (harness-converted)
    const float* W1l = (const float*)d_in[2];
    const float* b1  = (const float*)d_in[3];
    const float* W1r = (const float*)d_in[4];
    const float* W2l = (const float*)d_in[5];
    const float* b2  = (const float*)d_in[6];
    const float* W2r = (const float*)d_in[7];
    const float* W3l = (const float*)d_in[8];
    const float* b3  = (const float*)d_in[9];
    const float* W3r = (const float*)d_in[10];
    const float* Wl1 = (const float*)d_in[11];
    const float* bl1 = (const float*)d_in[12];
    const float* Wl2 = (const float*)d_in[13];
    const float* bl2 = (const float*)d_in[14];
    const float* Wl3 = (const float*)d_in[15];
    const float* bl3 = (const float*)d_in[16];
    float* out = (float*)d_out;

    const int N = in_sizes[0] / 9;
    const int E = in_sizes[1] / 2;

    char* ws = (char*)d_ws;
    size_t off = 0;
    auto alloc = [&](size_t bytes) -> void* {
        void* p = ws + off;
        off += (bytes + 255) & ~(size_t)255;
        return p;
    };
    __half* h16    = (__half*)alloc((size_t)N * 128 * sizeof(__half));  // 25.6 MB
    __half* agg16  = (__half*)alloc((size_t)N * 128 * sizeof(__half));  // 25.6 MB
    __half* a32    = (__half*)alloc((size_t)N * 32 * sizeof(__half));   // 6.4 MB
    int* rs     = (int*)alloc((size_t)(N + 1) * sizeof(int));
    int* csr    = (int*)alloc((size_t)E * sizeof(int));                  // 6.4 MB
    int* staged = (int*)alloc((size_t)E * sizeof(int));                  // 6.4 MB
    _Float16* wpk1  = (_Float16*)alloc(32 * 128 * sizeof(_Float16));
    _Float16* wpk2l = (_Float16*)alloc(128 * 128 * sizeof(_Float16));
    _Float16* wpk2r = (_Float16*)alloc(128 * 128 * sizeof(_Float16));
    _Float16* wpk3l = (_Float16*)alloc(128 * 128 * sizeof(_Float16));
    _Float16* wpk3r = (_Float16*)alloc(128 * 128 * sizeof(_Float16));
    _Float16* wpkl1 = (_Float16*)alloc(128 * 128 * sizeof(_Float16));
    _Float16* wpkl2 = (_Float16*)alloc(128 * 64 * sizeof(_Float16));
    (void)ws_size; (void)n_in; (void)out_size;

    // bucket params (N=100K, E=1.6M -> shift=7, NB=782, NBLK=782)
    int shift = 7;
    while ((((size_t)N + ((size_t)1 << shift) - 1) >> shift) > MAXNB) ++shift;
    const int NB = (N + (1 << shift) - 1) >> shift;
    const int NBLK = (E + CH - 1) / CH;               // must be <= MAXNBLK
    int* bh    = (int*)alloc((size_t)NB * NBLK * sizeof(int));          // 2.4 MB
    int* btot  = (int*)alloc((size_t)NB * sizeof(int));
    int* bbase = (int*)alloc((size_t)(NB + 1) * sizeof(int));
    int* bsum  = (int*)alloc(64 * sizeof(int));

    // Weight packing: one launch for the six K>=64 weights + layer-1 special
    WPD6 wp;
    wp.d[0] = {W2l, wpk2l, 128, 128};
    wp.d[1] = {W2r, wpk2r, 128, 128};
    wp.d[2] = {W3l, wpk3l, 128, 128};
    wp.d[3] = {W3r, wpk3r, 128, 128};
    wp.d[4] = {Wl1, wpkl1, 128, 128};
    wp.d[5] = {Wl2, wpkl2, 128, 64};
    wpack6_k<<<dim3(8, 6), 256, 0, stream>>>(wp);
    wpack1_k<<<2, 256, 0, stream>>>(W1l, W1r, wpk1);

    // CSR build (two-level bucket, no global-atomic scatter)
    bhist_k<<<NBLK, 256, 0, stream>>>(ei, bh, E, shift, NB, NBLK);
    scan_col_k<<<NB, 256, 0, stream>>>(bh, btot, NBLK, NB);
    scan_block_k<<<1, 256, 0, stream>>>(btot, bbase, bsum, NB);
    bscatter_k<<<NBLK, 256, 0, stream>>>(ei, bh, bbase, staged, E, shift, NB, NBLK);
    csrfill_k<<<NB, 256, 0, stream>>>(staged, bbase, rs, csr, N, E, shift, NB);

    const int gemm_grid = (N + 63) / 64;
    const int agg_grid = (N + 15) / 16;

    // SAGE layer 1 (9 -> 128): pack [agg9|x9|0] fp16, then K=32 MFMA GEMM
    agg9pack_k<<<(N + 255) / 256, 256, 0, stream>>>(x, rs, csr, a32, N);
    mfma_lin_k<2, 1, 32><<<gemm_grid, 256, 0, stream>>>(
        a32, nullptr, wpk1, nullptr, b1, h16, N);

    // SAGE layer 2 (128 -> 128): gather h1 -> agg16; h2 = relu(agg@W2l + h1@W2r + b2)
    agg128h4_k<<<agg_grid, 256, 0, stream>>>(h16, rs, csr, agg16, N);
    mfma_lin_k<2, 2, 128><<<gemm_grid, 256, 0, stream>>>(
        agg16, h16, wpk2l, wpk2r, b2, h16, N);

    // SAGE layer 3 (128 -> 128)
    agg128h4_k<<<agg_grid, 256, 0, stream>>>(h16, rs, csr, agg16, N);
    mfma_lin_k<2, 2, 128><<<gemm_grid, 256, 0, stream>>>(
        agg16, h16, wpk3l, wpk3r, b3, h16, N);

    // MLP: 128 -> 128 (relu) GEMM, then fused {128->64 relu GEMM + 64->3 +
    // log_softmax} tail
    mfma_lin_k<2, 1, 128><<<gemm_grid, 256, 0, stream>>>(
        h16, nullptr, wpkl1, nullptr, bl1, h16, N);
    mfma_lin_final_k<<<gemm_grid, 256, 0, stream>>>(
        h16, wpkl2, bl2, Wl3, bl3, out, N);
}